// Round 6
// baseline (822.253 us; speedup 1.0000x reference)
//
#include <hip/hip_runtime.h>
#include <hip/hip_fp16.h>

#define BATCH 4096
#define NCLS  4
#define INDIM 100
#define INITD 64
#define DD    164     // IN_DIM + INIT_DIM
#define DDP   192     // K padded to 6*32 for MFMA
#define MM    33      // PCAP + 1
#define TT    16
#define NOUT  16      // OUT_CAPS

typedef _Float16 f16;
typedef f16 f16x8 __attribute__((ext_vector_type(8)));
typedef float f32x4 __attribute__((ext_vector_type(4)));

// ======================= k_pre: entmax (bisection) + leaf norm =======================
// entmax15(x): x' = (x - max)/2; solve sum(clip(x'-tau,0)^2) = 1 by bisection.
// blocks 0..527: blk = m*16+n; 16 entmax problems (one per t), one per 16-lane group.
// block 528: m1 masks (3 waves) + leaves (wave 3). block 529: m2 masks (3 waves).
__global__ __launch_bounds__(256) void k_pre(const float* __restrict__ route_w,
    const float* __restrict__ m1_w, const float* __restrict__ m2_w,
    const float* __restrict__ leaves,
    __half* __restrict__ w2t, float* __restrict__ mask1, float* __restrict__ mask2,
    float* __restrict__ lh_t){
  int blk = blockIdx.x, tid = threadIdx.x;
  if (blk < 528){
    const float* base = route_w + (size_t)blk*DD*16;   // [164][16] slab for (m,n)
    int l  = tid & 63;
    int t  = (tid>>6)*4 + (l&3);
    int lg = l>>2;                                     // d = lg + 16*i
    float v[11];
    float mx = -1e30f;
    #pragma unroll
    for (int i=0;i<11;++i){
      int d = lg + 16*i;
      v[i] = (d < DD) ? base[d*16 + t] : -1e30f;
      mx = fmaxf(mx, v[i]);
    }
    #pragma unroll
    for (int msk=4; msk<=32; msk<<=1) mx = fmaxf(mx, __shfl_xor(mx, msk));
    #pragma unroll
    for (int i=0;i<11;++i) v[i] = (v[i]-mx)*0.5f;
    float lo=-1.0f, hi=0.0f;
    for (int it=0; it<30; ++it){
      float mid = 0.5f*(lo+hi), g=0.0f;
      #pragma unroll
      for (int i=0;i<11;++i){ float tv = fmaxf(v[i]-mid, 0.0f); g += tv*tv; }
      #pragma unroll
      for (int msk=4; msk<=32; msk<<=1) g += __shfl_xor(g, msk);
      if (g > 1.0f) lo = mid; else hi = mid;           // uniform branch
    }
    float tau = 0.5f*(lo+hi);
    __half* wout = w2t + (size_t)(blk*16 + t)*DDP;
    #pragma unroll
    for (int i=0;i<12;++i){
      int d = lg + 16*i;
      if (d < DDP){
        float tv = 0.0f;
        if (i < 11 && d < DD){ tv = fmaxf(v[i]-tau, 0.0f); }
        wout[d] = __float2half(tv*tv);
      }
    }
  } else if (blk == 528){
    int wv = tid>>6, l = tid&63;
    if (wv < 3){
      // entmax over m1_w[wv][0..63], one problem per wave
      float v0 = m1_w[wv*64 + l];
      float mx = v0;
      #pragma unroll
      for (int m=1;m<=32;m<<=1) mx = fmaxf(mx, __shfl_xor(mx,m));
      v0 = (v0-mx)*0.5f;
      float lo=-1.0f, hi=0.0f;
      for (int it=0;it<30;++it){
        float mid = 0.5f*(lo+hi);
        float tv = fmaxf(v0-mid, 0.0f);
        float g = tv*tv;
        #pragma unroll
        for (int m=1;m<=32;m<<=1) g += __shfl_xor(g,m);
        if (g > 1.0f) lo = mid; else hi = mid;
      }
      float tau = 0.5f*(lo+hi);
      float tv = fmaxf(v0-tau, 0.0f);
      mask1[wv*64 + l] = tv*tv;
    } else if (l < 32){
      int li = l;
      float s=0.0f;
      for (int t=0;t<TT;++t){ float vv=leaves[li*TT+t]; s+=vv*vv; }
      float dn = fmaxf(sqrtf(s), 1e-12f);
      for (int t=0;t<TT;++t) lh_t[t*32+li] = leaves[li*TT+t]/dn;  // transposed [t][l]
    }
  } else { // blk == 529: m2 masks, n=80 (64 lanes + 16 extra on lanes 0..15)
    int wv = tid>>6, l = tid&63;
    if (wv < 3){
      float v0 = m2_w[wv*80 + l];
      float v1 = (l < 16) ? m2_w[wv*80 + 64 + l] : -1e30f;
      float mx = fmaxf(v0, v1);
      #pragma unroll
      for (int m=1;m<=32;m<<=1) mx = fmaxf(mx, __shfl_xor(mx,m));
      v0 = (v0-mx)*0.5f; v1 = (v1-mx)*0.5f;
      float lo=-1.0f, hi=0.0f;
      for (int it=0;it<30;++it){
        float mid = 0.5f*(lo+hi);
        float t0 = fmaxf(v0-mid, 0.0f), t1 = fmaxf(v1-mid, 0.0f);
        float g = t0*t0 + t1*t1;
        #pragma unroll
        for (int m=1;m<=32;m<<=1) g += __shfl_xor(g,m);
        if (g > 1.0f) lo = mid; else hi = mid;
      }
      float tau = 0.5f*(lo+hi);
      float t0 = fmaxf(v0-tau, 0.0f);
      mask2[wv*80 + l] = t0*t0;
      if (l < 16){ float t1 = fmaxf(v1-tau, 0.0f); mask2[wv*80 + 64 + l] = t1*t1; }
    }
  }
}

// ======================= k_caps: encoder -> caps_t[m][bl][DDP] (f16, zero-padded) ====
__global__ __launch_bounds__(256) void k_caps(const float* __restrict__ x,
    const float* __restrict__ init_w, const float* __restrict__ init_b,
    const float* __restrict__ ln_g, const float* __restrict__ ln_b,
    const float* __restrict__ prim_fc, __half* __restrict__ caps_t, int b0, int nrows){
  int bl = blockIdx.x, b = b0 + bl, tid = threadIdx.x;
  __shared__ float f[DD], gs[DD], bs[DD], pfs[DD*32];
  if (tid < INDIM) f[tid] = x[(size_t)b*INDIM + tid];
  if (tid < DD){ gs[tid] = ln_g[tid]; bs[tid] = ln_b[tid]; }
  for (int i = tid; i < DD*32; i += 256) pfs[i] = prim_fc[i];
  __syncthreads();
  if (tid < INITD){
    float s = init_b[tid];
    for (int k=0;k<INDIM;++k) s += f[k]*init_w[tid*INDIM+k];
    f[INDIM+tid] = s;
  }
  __syncthreads();
  int w = tid>>6, lane = tid&63;
  for (int mi = w; mi < MM; mi += 4){
    float c[3]; float sum=0.0f, sq=0.0f;
    #pragma unroll
    for (int j=0;j<3;++j){
      int d = lane + 64*j;
      float v = 0.0f;
      if (d < DD) v = (mi < 32) ? f[d]*pfs[d*32+mi] : f[d];
      c[j] = v; sum += v; sq += v*v;
    }
    #pragma unroll
    for (int off=32; off; off>>=1){ sum += __shfl_xor(sum,off); sq += __shfl_xor(sq,off); }
    float mean = sum*(1.0f/DD);
    float var  = fmaxf(sq*(1.0f/DD) - mean*mean, 0.0f);
    float rstd = rsqrtf(var + 1e-5f);
    #pragma unroll
    for (int j=0;j<3;++j){
      int d = lane + 64*j;   // covers 0..191 exactly
      float o = (d < DD) ? ((c[j]-mean)*rstd*gs[d] + bs[d]) : 0.0f;
      caps_t[((size_t)mi*nrows + bl)*DDP + d] = __float2half(o);
    }
  }
}

// ======================= k_gemm_mfma: priors[bl][m][256] via 16x16x32 f16 MFMA =======
__global__ __launch_bounds__(256) void k_gemm_mfma(const f16* __restrict__ caps_t,
    const f16* __restrict__ w2t, __half* __restrict__ priors, int nrows){
  int m = blockIdx.y, b0 = blockIdx.x*64;
  int tid = threadIdx.x;
  int wave = tid>>6, lane = tid&63;
  __shared__ f16 Al[64][40];
  __shared__ f16 Wl[256][40];
  f32x4 acc[4][4];
  #pragma unroll
  for (int i=0;i<4;++i)
    #pragma unroll
    for (int j=0;j<4;++j) acc[i][j] = (f32x4){0.f,0.f,0.f,0.f};

  int ar = tid>>2, ac0 = (tid&3)*8;
  int rg = lane&15, kg = lane>>4;

  for (int kc = 0; kc < 6; ++kc){
    *(uint4*)&Al[ar][ac0] =
        *(const uint4*)&caps_t[((size_t)m*nrows + b0 + ar)*DDP + kc*32 + ac0];
    #pragma unroll
    for (int c=0;c<4;++c)
      *(uint4*)&Wl[tid][c*8] =
          *(const uint4*)&w2t[((size_t)m*256 + tid)*DDP + kc*32 + c*8];
    __syncthreads();
    f16x8 a[4], bf[4];
    #pragma unroll
    for (int i=0;i<4;++i) a[i]  = *(const f16x8*)&Al[i*16 + rg][kg*8];
    #pragma unroll
    for (int j=0;j<4;++j) bf[j] = *(const f16x8*)&Wl[wave*64 + j*16 + rg][kg*8];
    #pragma unroll
    for (int i=0;i<4;++i)
      #pragma unroll
      for (int j=0;j<4;++j)
        acc[i][j] = __builtin_amdgcn_mfma_f32_16x16x32_f16(a[i], bf[j], acc[i][j], 0, 0, 0);
    __syncthreads();
  }
  int rg4 = kg*4, cc = rg;
  #pragma unroll
  for (int i=0;i<4;++i)
    #pragma unroll
    for (int j=0;j<4;++j)
      #pragma unroll
      for (int r=0;r<4;++r)
        priors[(size_t)(b0 + i*16 + rg4 + r)*(MM*256) + m*256 + wave*64 + j*16 + cc]
            = __float2half(acc[i][j][r]);
}

// ======================= k_route: votes -> dis -> softmax -> hidden LN -> pred/hsel ===
__global__ __launch_bounds__(256) void k_route(const __half* __restrict__ priors,
    const float* __restrict__ lh_t, const float* __restrict__ thr_in,
    const float* __restrict__ cg, const float* __restrict__ cbv,
    const float* __restrict__ y, float* __restrict__ out_pred, float* __restrict__ hsel,
    int b0){
  int bl = blockIdx.x, b = b0 + bl, tid = threadIdx.x;
  __shared__ __half pr[MM*256];
  __shared__ float lhs[512];
  __shared__ float votes[8*MM*32];
  __shared__ float vmean[8*32];
  __shared__ float wp[8*MM];
  __shared__ float hid[16*16];
  __shared__ float nrm[16];
  __shared__ float yw[4];
  {
    const unsigned* pbw = (const unsigned*)(priors + (size_t)bl*(MM*256));
    unsigned* prw = (unsigned*)pr;
    for (int i = tid; i < (MM*256)/2; i += 256) prw[i] = pbw[i];
  }
  for (int i = tid; i < 512; i += 256) lhs[i] = lh_t[i];
  if (tid < 4) yw[tid] = y[(size_t)b*4 + tid];
  __syncthreads();

  for (int nc = 0; nc < 2; ++nc){
    int nl = tid >> 5, l = tid & 31, n = nc*8 + nl;
    for (int m=0;m<MM;++m){
      float s = 0.0f;
      const __half* p0 = &pr[m*256 + n*16];
      #pragma unroll
      for (int t=0;t<TT;++t) s += lhs[t*32+l]*__half2float(p0[t]);
      votes[(nl*MM+m)*32 + l] = 1.0f/(1.0f+__expf(-s));
    }
    __syncthreads();
    {
      float s = 0.0f;
      for (int m=0;m<MM;++m) s += votes[(nl*MM+m)*32 + l];
      vmean[nl*32+l] = s*(1.0f/MM);
    }
    __syncthreads();
    // 8*MM = 264 > 256 threads — grid-stride required
    for (int i = tid; i < 8*MM; i += 256){
      int nl2 = i/MM, m = i%MM, n2 = nc*8 + nl2;
      float s = 0.0f;
      for (int l2=0;l2<32;++l2){
        float dd = votes[(nl2*MM+m)*32+l2] - vmean[nl2*32+l2];
        s += dd*dd;
      }
      float dis = s*(1.0f/32);
      float th = thr_in[m*NOUT + n2];
      wp[nl2*MM+m] = fmaxf(th*th - dis, 0.0f);
    }
    __syncthreads();
    if (tid < 8){
      float mx = -1e30f;
      for (int m=0;m<MM;++m) mx = fmaxf(mx, wp[tid*MM+m]);
      float s = 0.0f;
      for (int m=0;m<MM;++m){ float e = expf(wp[tid*MM+m]-mx); wp[tid*MM+m] = e; s += e; }
      float inv = 1.0f/s;
      for (int m=0;m<MM;++m) wp[tid*MM+m] *= inv;
    }
    __syncthreads();
    if (tid < 128){
      int nl3 = tid >> 4, t = tid & 15, n3 = nc*8 + nl3;
      float s = 0.0f;
      for (int m=0;m<MM;++m) s += wp[nl3*MM+m]*__half2float(pr[m*256 + n3*16 + t]);
      hid[n3*16+t] = s;
    }
    __syncthreads();
  }
  if (tid < 16){
    float s=0.0f, q=0.0f;
    for (int t=0;t<TT;++t){ float v=hid[tid*16+t]; s+=v; q+=v*v; }
    float mean = s*(1.0f/TT);
    float var  = fmaxf(q*(1.0f/TT)-mean*mean, 0.0f);
    float rstd = rsqrtf(var + 1e-5f);
    float nn = 0.0f;
    for (int t=0;t<TT;++t){
      float v = (hid[tid*16+t]-mean)*rstd*cg[t] + cbv[t];
      hid[tid*16+t] = v; nn += v*v;
    }
    nrm[tid] = sqrtf(nn);
  }
  __syncthreads();
  if (tid < 4)
    out_pred[(size_t)b*4 + tid] = nrm[tid*4+0]+nrm[tid*4+1]+nrm[tid*4+2]+nrm[tid*4+3];
  if (tid < 64){
    int s2 = tid >> 4, t = tid & 15;
    float v = 0.0f;
    #pragma unroll
    for (int c=0;c<4;++c) v += yw[c]*hid[(s2*4+c)*16 + t];
    hsel[(size_t)b*64 + tid] = v;
  }
}

// ======================= k_dec1: h1 + GBN stats1 + GLU -> out1 (block per vbatch) ====
__global__ __launch_bounds__(512) void k_dec1(const float* __restrict__ hsel,
    const float* __restrict__ mask1, const float* __restrict__ fc1_w,
    const float* __restrict__ fc1_b, const float* __restrict__ bn1g,
    const float* __restrict__ bn1b, float* __restrict__ out1){
  int vb = blockIdx.x, tid = threadIdx.x;
  int r = tid>>1, half = tid&1;
  __shared__ __half h1s[256][97];
  __shared__ float mk[3][64];
  __shared__ float stat[96][2];
  for (int i=tid; i<192; i+=512) mk[i>>6][i&63] = mask1[i];
  __syncthreads();
  float hs[64];
  {
    const float4* h4 = (const float4*)(hsel + ((size_t)(vb*256 + r))*64);
    #pragma unroll
    for (int i=0;i<16;++i){ float4 v = h4[i]; hs[4*i]=v.x; hs[4*i+1]=v.y; hs[4*i+2]=v.z; hs[4*i+3]=v.w; }
  }
  for (int jj=0; jj<48; ++jj){
    int j = half*48 + jj;
    int p = j>>5;
    const float* wr = fc1_w + j*64;
    float s = fc1_b[j];
    #pragma unroll 8
    for (int d=0; d<64; ++d) s += mk[p][d]*hs[d]*wr[d];
    h1s[r][j] = __float2half(s);
  }
  __syncthreads();
  if (tid < 96){
    float s=0.0f, q=0.0f;
    for (int r2=0; r2<256; ++r2){ float v = __half2float(h1s[r2][tid]); s+=v; q+=v*v; }
    float mean = s*(1.0f/256);
    float var  = fmaxf(q*(1.0f/256) - mean*mean, 0.0f);
    stat[tid][0] = mean; stat[tid][1] = rsqrtf(var + 1e-5f);
  }
  __syncthreads();
  if (half == 0){
    for (int q=0; q<16; ++q){
      float s = 0.0f;
      #pragma unroll
      for (int p=0;p<3;++p){
        int ja = p*32+q, jb = ja+16;
        float ha = (__half2float(h1s[r][ja])-stat[ja][0])*stat[ja][1]*bn1g[ja] + bn1b[ja];
        float hb = (__half2float(h1s[r][jb])-stat[jb][0])*stat[jb][1]*bn1g[jb] + bn1b[jb];
        s += fmaxf(hb/(1.0f+expf(-ha)), 0.0f);
      }
      out1[((size_t)(vb*256 + r))*16 + q] = s;
    }
  }
}

// ======================= k_dec2: h2 + GBN stats2 + GLU + final linear ================
__global__ __launch_bounds__(768) void k_dec2(const float* __restrict__ hsel,
    const float* __restrict__ out1, const float* __restrict__ mask2,
    const float* __restrict__ fc2_w, const float* __restrict__ fc2_b,
    const float* __restrict__ bn2g, const float* __restrict__ bn2b,
    const float* __restrict__ dec_w, const float* __restrict__ dec_b,
    __half* __restrict__ h2g, float* __restrict__ rec){
  int vb = blockIdx.x, tid = threadIdx.x;
  __shared__ __align__(16) __half h2s_[256][88];   // staged inputs [hsel|out1] f16
  __shared__ float mk2[3][80];
  __shared__ float ps2[4][192], pq2[4][192];
  __shared__ float stat2[192][2];
  for (int i=tid; i<240; i+=768) mk2[i/80][i%80] = mask2[i];
  for (int i=tid; i<256*80; i+=768){
    int r = i/80, d = i - 80*r;
    float v = (d < 64) ? hsel[((size_t)(vb*256+r))*64 + d]
                       : out1[((size_t)(vb*256+r))*16 + (d-64)];
    h2s_[r][d] = __float2half(v);
  }
  __syncthreads();
  // phase B: h2 columns; 4 row-segments x 192 columns
  {
    int h = tid/192, j = tid - h*192;   // 768 = 4*192 exactly
    int p = j>>6;
    float mwv[80];
    const float* wr = fc2_w + j*80;
    #pragma unroll 8
    for (int d=0; d<80; ++d) mwv[d] = mk2[p][d]*wr[d];
    float bias = fc2_b[j];
    float sum=0.0f, sq=0.0f;
    for (int rr=0; rr<64; ++rr){
      int r = h*64 + rr;
      float s = bias;
      #pragma unroll
      for (int d8=0; d8<10; ++d8){
        f16x8 hv = *(const f16x8*)&h2s_[r][d8*8];
        #pragma unroll
        for (int u=0;u<8;++u) s += mwv[d8*8+u]*(float)hv[u];
      }
      h2g[((size_t)(vb*256+r))*192 + j] = __float2half(s);
      sum += s; sq += s*s;
    }
    ps2[h][j] = sum; pq2[h][j] = sq;
  }
  __syncthreads();
  if (tid < 192){
    float s = ps2[0][tid]+ps2[1][tid]+ps2[2][tid]+ps2[3][tid];
    float q = pq2[0][tid]+pq2[1][tid]+pq2[2][tid]+pq2[3][tid];
    float mean = s*(1.0f/256);
    float var  = fmaxf(q*(1.0f/256) - mean*mean, 0.0f);
    stat2[tid][0] = mean; stat2[tid][1] = rsqrtf(var + 1e-5f);
  }
  __syncthreads();
  // phase C: normalize + GLU + final linear (3 segments over output k)
  {
    int r = tid & 255, seg = tid >> 8;
    const __half* hrow = h2g + ((size_t)(vb*256+r))*192;
    float o2[32];
    #pragma unroll 4
    for (int q=0; q<32; ++q){
      float s = 0.0f;
      #pragma unroll
      for (int p=0;p<3;++p){
        int ja = p*64+q, jb = ja+32;
        float na = (__half2float(hrow[ja])-stat2[ja][0])*stat2[ja][1]*bn2g[ja] + bn2b[ja];
        float nb = (__half2float(hrow[jb])-stat2[jb][0])*stat2[jb][1]*bn2g[jb] + bn2b[jb];
        s += fmaxf(nb/(1.0f+expf(-na)), 0.0f);
      }
      o2[q] = s;
    }
    for (int k=seg; k<INDIM; k+=3){
      float rv = dec_b[k];
      const float* dwr = dec_w + k*32;
      #pragma unroll
      for (int q=0;q<32;++q) rv += o2[q]*dwr[q];
      rec[((size_t)(vb*256+r))*INDIM + k] = rv;
    }
  }
}

// ======================= launch =======================
extern "C" void kernel_launch(void* const* d_in, const int* in_sizes, int n_in,
                              void* d_out, int out_size, void* d_ws, size_t ws_size,
                              hipStream_t stream){
  const float* x      = (const float*)d_in[0];
  const float* y      = (const float*)d_in[1];
  const float* init_w = (const float*)d_in[2];
  const float* init_b = (const float*)d_in[3];
  const float* eg     = (const float*)d_in[4];
  const float* ebv    = (const float*)d_in[5];
  const float* pf     = (const float*)d_in[6];
  const float* rw     = (const float*)d_in[7];
  const float* thr    = (const float*)d_in[8];
  const float* lv     = (const float*)d_in[9];
  const float* cg     = (const float*)d_in[10];
  const float* cbv    = (const float*)d_in[11];
  const float* m1w    = (const float*)d_in[12];
  const float* f1w    = (const float*)d_in[13];
  const float* f1b    = (const float*)d_in[14];
  const float* g1     = (const float*)d_in[15];
  const float* b1     = (const float*)d_in[16];
  const float* m2w    = (const float*)d_in[17];
  const float* f2w    = (const float*)d_in[18];
  const float* f2b    = (const float*)d_in[19];
  const float* g2     = (const float*)d_in[20];
  const float* b2v    = (const float*)d_in[21];
  const float* dw     = (const float*)d_in[22];
  const float* db     = (const float*)d_in[23];
  char* ws = (char*)d_ws;
  float* out = (float*)d_out;
  (void)in_sizes; (void)n_in; (void)out_size;

  // layout: [w2, caps, priors, m1, m2, lh, hsel, out1, h2g]
  size_t offs[9];
  auto layout = [&](size_t nrows)->size_t{
    size_t o = 0; int i = 0;
    auto put = [&](size_t bytes){ offs[i++] = o; o = (o + bytes + 255) & ~(size_t)255; };
    put((size_t)MM*256*DDP*sizeof(__half));
    put((size_t)MM*nrows*DDP*sizeof(__half));
    put((size_t)nrows*MM*256*sizeof(__half));
    put(192*sizeof(float));
    put(240*sizeof(float));
    put(512*sizeof(float));
    put((size_t)BATCH*64*sizeof(float));
    put((size_t)BATCH*16*sizeof(float));
    put((size_t)BATCH*192*sizeof(__half));
    return o;
  };
  int nrows = BATCH, nchunk = 1;
  if (layout(BATCH) > ws_size){ nrows = 1024; nchunk = 4; layout(1024); }
  __half* w2   = (__half*)(ws + offs[0]);
  __half* caps = (__half*)(ws + offs[1]);
  __half* pri  = (__half*)(ws + offs[2]);
  float*  m1   = (float*)(ws + offs[3]);
  float*  m2   = (float*)(ws + offs[4]);
  float*  lh   = (float*)(ws + offs[5]);
  float*  hsel = (float*)(ws + offs[6]);
  float*  out1 = (float*)(ws + offs[7]);
  __half* h2g  = (__half*)(ws + offs[8]);

  k_pre<<<dim3(530), dim3(256), 0, stream>>>(rw, m1w, m2w, lv, w2, m1, m2, lh);

  for (int c = 0; c < nchunk; ++c){
    int b0 = c*nrows;
    k_caps<<<dim3(nrows), dim3(256), 0, stream>>>(x, init_w, init_b, eg, ebv, pf,
        caps, b0, nrows);
    k_gemm_mfma<<<dim3(nrows/64, MM), dim3(256), 0, stream>>>(
        (const f16*)caps, (const f16*)w2, pri, nrows);
    k_route<<<dim3(nrows), dim3(256), 0, stream>>>(pri, lh, thr, cg, cbv, y,
        out, hsel, b0);
  }

  k_dec1<<<dim3(16), dim3(512), 0, stream>>>(hsel, m1, f1w, f1b, g1, b1, out1);
  k_dec2<<<dim3(16), dim3(768), 0, stream>>>(hsel, out1, m2, f2w, f2b, g2, b2v,
      dw, db, h2g, out + (size_t)BATCH*NCLS);
}

// Round 8
// 489.164 us; speedup vs baseline: 1.6809x; 1.6809x over previous
//
#include <hip/hip_runtime.h>
#include <hip/hip_fp16.h>

#define BATCH 4096
#define NCLS  4
#define INDIM 100
#define INITD 64
#define DD    164     // IN_DIM + INIT_DIM
#define DDP   192     // K padded to 6*32 for MFMA
#define MM    33      // PCAP + 1
#define TT    16
#define NOUT  16      // OUT_CAPS

typedef _Float16 f16;
typedef f16 f16x8 __attribute__((ext_vector_type(8)));
typedef float f32x4 __attribute__((ext_vector_type(4)));

// ======================= k_pre: entmax (bisection) + leaf norm =======================
// entmax15(x): x' = (x - max)/2; solve sum(clip(x'-tau,0)^2) = 1 by bisection.
// blocks 0..527: blk = m*16+n; 16 entmax problems (one per t), one per 16-lane group.
// block 528: m1 masks (3 waves) + leaves (wave 3). block 529: m2 masks (3 waves).
__global__ __launch_bounds__(256) void k_pre(const float* __restrict__ route_w,
    const float* __restrict__ m1_w, const float* __restrict__ m2_w,
    const float* __restrict__ leaves,
    __half* __restrict__ w2t, float* __restrict__ mask1, float* __restrict__ mask2,
    float* __restrict__ lh_t){
  int blk = blockIdx.x, tid = threadIdx.x;
  if (blk < 528){
    const float* base = route_w + (size_t)blk*DD*16;   // [164][16] slab for (m,n)
    int l  = tid & 63;
    int t  = (tid>>6)*4 + (l&3);
    int lg = l>>2;                                     // d = lg + 16*i
    float v[11];
    float mx = -1e30f;
    #pragma unroll
    for (int i=0;i<11;++i){
      int d = lg + 16*i;
      v[i] = (d < DD) ? base[d*16 + t] : -1e30f;
      mx = fmaxf(mx, v[i]);
    }
    #pragma unroll
    for (int msk=4; msk<=32; msk<<=1) mx = fmaxf(mx, __shfl_xor(mx, msk));
    #pragma unroll
    for (int i=0;i<11;++i) v[i] = (v[i]-mx)*0.5f;
    float lo=-1.0f, hi=0.0f;
    for (int it=0; it<30; ++it){
      float mid = 0.5f*(lo+hi), g=0.0f;
      #pragma unroll
      for (int i=0;i<11;++i){ float tv = fmaxf(v[i]-mid, 0.0f); g += tv*tv; }
      #pragma unroll
      for (int msk=4; msk<=32; msk<<=1) g += __shfl_xor(g, msk);
      if (g > 1.0f) lo = mid; else hi = mid;           // uniform branch
    }
    float tau = 0.5f*(lo+hi);
    __half* wout = w2t + (size_t)(blk*16 + t)*DDP;
    #pragma unroll
    for (int i=0;i<12;++i){
      int d = lg + 16*i;
      if (d < DDP){
        float tv = 0.0f;
        if (i < 11 && d < DD){ tv = fmaxf(v[i]-tau, 0.0f); }
        wout[d] = __float2half(tv*tv);
      }
    }
  } else if (blk == 528){
    int wv = tid>>6, l = tid&63;
    if (wv < 3){
      float v0 = m1_w[wv*64 + l];
      float mx = v0;
      #pragma unroll
      for (int m=1;m<=32;m<<=1) mx = fmaxf(mx, __shfl_xor(mx,m));
      v0 = (v0-mx)*0.5f;
      float lo=-1.0f, hi=0.0f;
      for (int it=0;it<30;++it){
        float mid = 0.5f*(lo+hi);
        float tv = fmaxf(v0-mid, 0.0f);
        float g = tv*tv;
        #pragma unroll
        for (int m=1;m<=32;m<<=1) g += __shfl_xor(g,m);
        if (g > 1.0f) lo = mid; else hi = mid;
      }
      float tau = 0.5f*(lo+hi);
      float tv = fmaxf(v0-tau, 0.0f);
      mask1[wv*64 + l] = tv*tv;
    } else if (l < 32){
      int li = l;
      float s=0.0f;
      for (int t=0;t<TT;++t){ float vv=leaves[li*TT+t]; s+=vv*vv; }
      float dn = fmaxf(sqrtf(s), 1e-12f);
      for (int t=0;t<TT;++t) lh_t[t*32+li] = leaves[li*TT+t]/dn;  // transposed [t][l]
    }
  } else { // blk == 529: m2 masks, n=80
    int wv = tid>>6, l = tid&63;
    if (wv < 3){
      float v0 = m2_w[wv*80 + l];
      float v1 = (l < 16) ? m2_w[wv*80 + 64 + l] : -1e30f;
      float mx = fmaxf(v0, v1);
      #pragma unroll
      for (int m=1;m<=32;m<<=1) mx = fmaxf(mx, __shfl_xor(mx,m));
      v0 = (v0-mx)*0.5f; v1 = (v1-mx)*0.5f;
      float lo=-1.0f, hi=0.0f;
      for (int it=0;it<30;++it){
        float mid = 0.5f*(lo+hi);
        float t0 = fmaxf(v0-mid, 0.0f), t1 = fmaxf(v1-mid, 0.0f);
        float g = t0*t0 + t1*t1;
        #pragma unroll
        for (int m=1;m<=32;m<<=1) g += __shfl_xor(g,m);
        if (g > 1.0f) lo = mid; else hi = mid;
      }
      float tau = 0.5f*(lo+hi);
      float t0 = fmaxf(v0-tau, 0.0f);
      mask2[wv*80 + l] = t0*t0;
      if (l < 16){ float t1 = fmaxf(v1-tau, 0.0f); mask2[wv*80 + 64 + l] = t1*t1; }
    }
  }
}

// ======================= k_caps: encoder -> caps_t[m][bl][DDP] (f16, zero-padded) ====
__global__ __launch_bounds__(256) void k_caps(const float* __restrict__ x,
    const float* __restrict__ init_w, const float* __restrict__ init_b,
    const float* __restrict__ ln_g, const float* __restrict__ ln_b,
    const float* __restrict__ prim_fc, __half* __restrict__ caps_t, int b0, int nrows){
  int bl = blockIdx.x, b = b0 + bl, tid = threadIdx.x;
  __shared__ float f[DD], gs[DD], bs[DD], pfs[DD*32];
  if (tid < INDIM) f[tid] = x[(size_t)b*INDIM + tid];
  if (tid < DD){ gs[tid] = ln_g[tid]; bs[tid] = ln_b[tid]; }
  for (int i = tid; i < DD*32; i += 256) pfs[i] = prim_fc[i];
  __syncthreads();
  if (tid < INITD){
    float s = init_b[tid];
    for (int k=0;k<INDIM;++k) s += f[k]*init_w[tid*INDIM+k];
    f[INDIM+tid] = s;
  }
  __syncthreads();
  int w = tid>>6, lane = tid&63;
  for (int mi = w; mi < MM; mi += 4){
    float c[3]; float sum=0.0f, sq=0.0f;
    #pragma unroll
    for (int j=0;j<3;++j){
      int d = lane + 64*j;
      float v = 0.0f;
      if (d < DD) v = (mi < 32) ? f[d]*pfs[d*32+mi] : f[d];
      c[j] = v; sum += v; sq += v*v;
    }
    #pragma unroll
    for (int off=32; off; off>>=1){ sum += __shfl_xor(sum,off); sq += __shfl_xor(sq,off); }
    float mean = sum*(1.0f/DD);
    float var  = fmaxf(sq*(1.0f/DD) - mean*mean, 0.0f);
    float rstd = rsqrtf(var + 1e-5f);
    #pragma unroll
    for (int j=0;j<3;++j){
      int d = lane + 64*j;   // covers 0..191 exactly
      float o = (d < DD) ? ((c[j]-mean)*rstd*gs[d] + bs[d]) : 0.0f;
      caps_t[((size_t)mi*nrows + bl)*DDP + d] = __float2half(o);
    }
  }
}

// ======================= k_gemm_mfma: priors[bl][m][256] via 16x16x32 f16 MFMA =======
__global__ __launch_bounds__(256) void k_gemm_mfma(const f16* __restrict__ caps_t,
    const f16* __restrict__ w2t, __half* __restrict__ priors, int nrows){
  int m = blockIdx.y, b0 = blockIdx.x*64;
  int tid = threadIdx.x;
  int wave = tid>>6, lane = tid&63;
  __shared__ f16 Al[64][40];
  __shared__ f16 Wl[256][40];
  f32x4 acc[4][4];
  #pragma unroll
  for (int i=0;i<4;++i)
    #pragma unroll
    for (int j=0;j<4;++j) acc[i][j] = (f32x4){0.f,0.f,0.f,0.f};

  int ar = tid>>2, ac0 = (tid&3)*8;
  int rg = lane&15, kg = lane>>4;

  for (int kc = 0; kc < 6; ++kc){
    *(uint4*)&Al[ar][ac0] =
        *(const uint4*)&caps_t[((size_t)m*nrows + b0 + ar)*DDP + kc*32 + ac0];
    #pragma unroll
    for (int c=0;c<4;++c)
      *(uint4*)&Wl[tid][c*8] =
          *(const uint4*)&w2t[((size_t)m*256 + tid)*DDP + kc*32 + c*8];
    __syncthreads();
    f16x8 a[4], bf[4];
    #pragma unroll
    for (int i=0;i<4;++i) a[i]  = *(const f16x8*)&Al[i*16 + rg][kg*8];
    #pragma unroll
    for (int j=0;j<4;++j) bf[j] = *(const f16x8*)&Wl[wave*64 + j*16 + rg][kg*8];
    #pragma unroll
    for (int i=0;i<4;++i)
      #pragma unroll
      for (int j=0;j<4;++j)
        acc[i][j] = __builtin_amdgcn_mfma_f32_16x16x32_f16(a[i], bf[j], acc[i][j], 0, 0, 0);
    __syncthreads();
  }
  int rg4 = kg*4, cc = rg;
  #pragma unroll
  for (int i=0;i<4;++i)
    #pragma unroll
    for (int j=0;j<4;++j)
      #pragma unroll
      for (int r=0;r<4;++r)
        priors[(size_t)(b0 + i*16 + rg4 + r)*(MM*256) + m*256 + wave*64 + j*16 + cc]
            = __float2half(acc[i][j][r]);
}

// ======================= k_route: votes -> dis -> softmax -> hidden LN -> pred/hsel ===
__global__ __launch_bounds__(256) void k_route(const __half* __restrict__ priors,
    const float* __restrict__ lh_t, const float* __restrict__ thr_in,
    const float* __restrict__ cg, const float* __restrict__ cbv,
    const float* __restrict__ y, float* __restrict__ out_pred, float* __restrict__ hsel,
    int b0){
  int bl = blockIdx.x, b = b0 + bl, tid = threadIdx.x;
  __shared__ __half pr[MM*256];
  __shared__ float lhs[512];
  __shared__ float votes[8*MM*32];
  __shared__ float vmean[8*32];
  __shared__ float wp[8*MM];
  __shared__ float hid[16*16];
  __shared__ float nrm[16];
  __shared__ float yw[4];
  {
    const unsigned* pbw = (const unsigned*)(priors + (size_t)bl*(MM*256));
    unsigned* prw = (unsigned*)pr;
    for (int i = tid; i < (MM*256)/2; i += 256) prw[i] = pbw[i];
  }
  for (int i = tid; i < 512; i += 256) lhs[i] = lh_t[i];
  if (tid < 4) yw[tid] = y[(size_t)b*4 + tid];
  __syncthreads();

  for (int nc = 0; nc < 2; ++nc){
    int nl = tid >> 5, l = tid & 31, n = nc*8 + nl;
    for (int m=0;m<MM;++m){
      float s = 0.0f;
      const __half* p0 = &pr[m*256 + n*16];
      #pragma unroll
      for (int t=0;t<TT;++t) s += lhs[t*32+l]*__half2float(p0[t]);
      votes[(nl*MM+m)*32 + l] = 1.0f/(1.0f+__expf(-s));
    }
    __syncthreads();
    {
      float s = 0.0f;
      for (int m=0;m<MM;++m) s += votes[(nl*MM+m)*32 + l];
      vmean[nl*32+l] = s*(1.0f/MM);
    }
    __syncthreads();
    // 8*MM = 264 > 256 threads — grid-stride required
    for (int i = tid; i < 8*MM; i += 256){
      int nl2 = i/MM, m = i%MM, n2 = nc*8 + nl2;
      float s = 0.0f;
      for (int l2=0;l2<32;++l2){
        float dd = votes[(nl2*MM+m)*32+l2] - vmean[nl2*32+l2];
        s += dd*dd;
      }
      float dis = s*(1.0f/32);
      float th = thr_in[m*NOUT + n2];
      wp[nl2*MM+m] = fmaxf(th*th - dis, 0.0f);
    }
    __syncthreads();
    if (tid < 8){
      float mx = -1e30f;
      for (int m=0;m<MM;++m) mx = fmaxf(mx, wp[tid*MM+m]);
      float s = 0.0f;
      for (int m=0;m<MM;++m){ float e = expf(wp[tid*MM+m]-mx); wp[tid*MM+m] = e; s += e; }
      float inv = 1.0f/s;
      for (int m=0;m<MM;++m) wp[tid*MM+m] *= inv;
    }
    __syncthreads();
    if (tid < 128){
      int nl3 = tid >> 4, t = tid & 15, n3 = nc*8 + nl3;
      float s = 0.0f;
      for (int m=0;m<MM;++m) s += wp[nl3*MM+m]*__half2float(pr[m*256 + n3*16 + t]);
      hid[n3*16+t] = s;
    }
    __syncthreads();
  }
  if (tid < 16){
    float s=0.0f, q=0.0f;
    for (int t=0;t<TT;++t){ float v=hid[tid*16+t]; s+=v; q+=v*v; }
    float mean = s*(1.0f/TT);
    float var  = fmaxf(q*(1.0f/TT)-mean*mean, 0.0f);
    float rstd = rsqrtf(var + 1e-5f);
    float nn = 0.0f;
    for (int t=0;t<TT;++t){
      float v = (hid[tid*16+t]-mean)*rstd*cg[t] + cbv[t];
      hid[tid*16+t] = v; nn += v*v;
    }
    nrm[tid] = sqrtf(nn);
  }
  __syncthreads();
  if (tid < 4)
    out_pred[(size_t)b*4 + tid] = nrm[tid*4+0]+nrm[tid*4+1]+nrm[tid*4+2]+nrm[tid*4+3];
  if (tid < 64){
    int s2 = tid >> 4, t = tid & 15;
    float v = 0.0f;
    #pragma unroll
    for (int c=0;c<4;++c) v += yw[c]*hid[(s2*4+c)*16 + t];
    hsel[(size_t)b*64 + tid] = v;
  }
}

// ======================= decoder (wide-grid, round-5 style) ==========================
__global__ __launch_bounds__(256) void k_h1(const float* __restrict__ hsel,
    const float* __restrict__ mask1, const float* __restrict__ fc1_w,
    const float* __restrict__ fc1_b, float* __restrict__ h1){
  int idx = blockIdx.x*256 + threadIdx.x;
  if (idx >= BATCH*96) return;
  int b = idx/96, j = idx%96, p = j>>5;
  float s = fc1_b[j];
  const float* hs = hsel + (size_t)b*64;
  const float* mk = mask1 + p*64;
  const float* wr = fc1_w + (size_t)j*64;
  for (int d=0; d<64; ++d) s += mk[d]*hs[d]*wr[d];
  h1[idx] = s;
}

__global__ __launch_bounds__(256) void k_stats(const float* __restrict__ h,
    float* __restrict__ stats, int F){
  int vb = blockIdx.x / F, j = blockIdx.x % F;
  float v = h[(size_t)(vb*256 + threadIdx.x)*F + j];
  float s = v, q = v*v;
  #pragma unroll
  for (int off=32; off; off>>=1){ s += __shfl_xor(s,off); q += __shfl_xor(q,off); }
  __shared__ float ps[4], pq[4];
  int w = threadIdx.x >> 6;
  if ((threadIdx.x & 63) == 0){ ps[w]=s; pq[w]=q; }
  __syncthreads();
  if (threadIdx.x == 0){
    float ss = ps[0]+ps[1]+ps[2]+ps[3];
    float qq = pq[0]+pq[1]+pq[2]+pq[3];
    float mean = ss*(1.0f/256);
    float var  = fmaxf(qq*(1.0f/256) - mean*mean, 0.0f);
    stats[(size_t)blockIdx.x*2]   = mean;
    stats[(size_t)blockIdx.x*2+1] = rsqrtf(var + 1e-5f);
  }
}

__global__ __launch_bounds__(192) void k_out1h2(const float* __restrict__ hsel,
    const float* __restrict__ h1, const float* __restrict__ stats1,
    const float* __restrict__ bn1g, const float* __restrict__ bn1b,
    const float* __restrict__ mask2, const float* __restrict__ fc2_w,
    const float* __restrict__ fc2_b, float* __restrict__ h2raw){
  int b = blockIdx.x, tid = threadIdx.x, vb = b >> 8;
  __shared__ float h2s[80];
  if (tid < 64) h2s[tid] = hsel[(size_t)b*64 + tid];
  if (tid < 16){
    float s = 0.0f;
    for (int p=0;p<3;++p){
      int ja = p*32 + tid, jb = ja + 16;
      float ha = (h1[(size_t)b*96+ja]-stats1[(vb*96+ja)*2])*stats1[(vb*96+ja)*2+1]*bn1g[ja] + bn1b[ja];
      float hb = (h1[(size_t)b*96+jb]-stats1[(vb*96+jb)*2])*stats1[(vb*96+jb)*2+1]*bn1g[jb] + bn1b[jb];
      float sg = 1.0f/(1.0f+expf(-ha));
      s += fmaxf(sg*hb, 0.0f);
    }
    h2s[64+tid] = s;
  }
  __syncthreads();
  int p = tid >> 6;
  float s = fc2_b[tid];
  const float* mk = mask2 + p*80;
  const float* wr = fc2_w + (size_t)tid*80;
  for (int d=0; d<80; ++d) s += mk[d]*h2s[d]*wr[d];
  h2raw[(size_t)b*192 + tid] = s;
}

__global__ __launch_bounds__(128) void k_final(const float* __restrict__ h2raw,
    const float* __restrict__ stats2, const float* __restrict__ bn2g,
    const float* __restrict__ bn2b, const float* __restrict__ dec_w,
    const float* __restrict__ dec_b, float* __restrict__ out_rec){
  int b = blockIdx.x, tid = threadIdx.x, vb = b >> 8;
  __shared__ float o2[32];
  if (tid < 32){
    float s = 0.0f;
    for (int p=0;p<3;++p){
      int ja = p*64 + tid, jb = ja + 32;
      float ha = (h2raw[(size_t)b*192+ja]-stats2[(vb*192+ja)*2])*stats2[(vb*192+ja)*2+1]*bn2g[ja] + bn2b[ja];
      float hb = (h2raw[(size_t)b*192+jb]-stats2[(vb*192+jb)*2])*stats2[(vb*192+jb)*2+1]*bn2g[jb] + bn2b[jb];
      float sg = 1.0f/(1.0f+expf(-ha));
      s += fmaxf(sg*hb, 0.0f);
    }
    o2[tid] = s;
  }
  __syncthreads();
  if (tid < INDIM){
    float r = dec_b[tid];
    #pragma unroll
    for (int o=0;o<32;++o) r += o2[o]*dec_w[tid*32+o];
    out_rec[(size_t)b*INDIM + tid] = r;
  }
}

// ======================= launch =======================
extern "C" void kernel_launch(void* const* d_in, const int* in_sizes, int n_in,
                              void* d_out, int out_size, void* d_ws, size_t ws_size,
                              hipStream_t stream){
  const float* x      = (const float*)d_in[0];
  const float* y      = (const float*)d_in[1];
  const float* init_w = (const float*)d_in[2];
  const float* init_b = (const float*)d_in[3];
  const float* eg     = (const float*)d_in[4];
  const float* ebv    = (const float*)d_in[5];
  const float* pf     = (const float*)d_in[6];
  const float* rw     = (const float*)d_in[7];
  const float* thr    = (const float*)d_in[8];
  const float* lv     = (const float*)d_in[9];
  const float* cg     = (const float*)d_in[10];
  const float* cbv    = (const float*)d_in[11];
  const float* m1w    = (const float*)d_in[12];
  const float* f1w    = (const float*)d_in[13];
  const float* f1b    = (const float*)d_in[14];
  const float* g1     = (const float*)d_in[15];
  const float* b1     = (const float*)d_in[16];
  const float* m2w    = (const float*)d_in[17];
  const float* f2w    = (const float*)d_in[18];
  const float* f2b    = (const float*)d_in[19];
  const float* g2     = (const float*)d_in[20];
  const float* b2v    = (const float*)d_in[21];
  const float* dw     = (const float*)d_in[22];
  const float* db     = (const float*)d_in[23];
  char* ws = (char*)d_ws;
  float* out = (float*)d_out;
  (void)in_sizes; (void)n_in; (void)out_size;

  // layout: [w2, caps, priors, m1, m2, lh, hsel, h1, s1, h2, s2]
  size_t offs[11];
  auto layout = [&](size_t nrows)->size_t{
    size_t o = 0; int i = 0;
    auto put = [&](size_t bytes){ offs[i++] = o; o = (o + bytes + 255) & ~(size_t)255; };
    put((size_t)MM*256*DDP*sizeof(__half));
    put((size_t)MM*nrows*DDP*sizeof(__half));
    put((size_t)nrows*MM*256*sizeof(__half));
    put(192*sizeof(float));
    put(240*sizeof(float));
    put(512*sizeof(float));
    put((size_t)BATCH*64*sizeof(float));
    put((size_t)BATCH*96*sizeof(float));
    put(16*96*2*sizeof(float));
    put((size_t)BATCH*192*sizeof(float));
    put(16*192*2*sizeof(float));
    return o;
  };
  int nrows = BATCH, nchunk = 1;
  if (layout(BATCH) > ws_size){ nrows = 1024; nchunk = 4; layout(1024); }
  __half* w2   = (__half*)(ws + offs[0]);
  __half* caps = (__half*)(ws + offs[1]);
  __half* pri  = (__half*)(ws + offs[2]);
  float*  m1   = (float*)(ws + offs[3]);
  float*  m2   = (float*)(ws + offs[4]);
  float*  lh   = (float*)(ws + offs[5]);
  float*  hsel = (float*)(ws + offs[6]);
  float*  h1   = (float*)(ws + offs[7]);
  float*  s1   = (float*)(ws + offs[8]);
  float*  h2   = (float*)(ws + offs[9]);
  float*  s2   = (float*)(ws + offs[10]);

  k_pre<<<dim3(530), dim3(256), 0, stream>>>(rw, m1w, m2w, lv, w2, m1, m2, lh);

  for (int c = 0; c < nchunk; ++c){
    int b0 = c*nrows;
    k_caps<<<dim3(nrows), dim3(256), 0, stream>>>(x, init_w, init_b, eg, ebv, pf,
        caps, b0, nrows);
    k_gemm_mfma<<<dim3(nrows/64, MM), dim3(256), 0, stream>>>(
        (const f16*)caps, (const f16*)w2, pri, nrows);
    k_route<<<dim3(nrows), dim3(256), 0, stream>>>(pri, lh, thr, cg, cbv, y,
        out, hsel, b0);
  }

  k_h1<<<dim3((BATCH*96)/256), dim3(256), 0, stream>>>(hsel, m1, f1w, f1b, h1);
  k_stats<<<dim3(16*96), dim3(256), 0, stream>>>(h1, s1, 96);
  k_out1h2<<<dim3(BATCH), dim3(192), 0, stream>>>(hsel, h1, s1, g1, b1,
      m2, f2w, f2b, h2);
  k_stats<<<dim3(16*192), dim3(256), 0, stream>>>(h2, s2, 192);
  k_final<<<dim3(BATCH), dim3(128), 0, stream>>>(h2, s2, g2, b2v, dw, db,
      out + (size_t)BATCH*NCLS);
}

// Round 9
// 468.588 us; speedup vs baseline: 1.7547x; 1.0439x over previous
//
#include <hip/hip_runtime.h>
#include <hip/hip_fp16.h>

#define BATCH 4096
#define NCLS  4
#define INDIM 100
#define INITD 64
#define DD    164     // IN_DIM + INIT_DIM
#define DDP   192     // K padded to 6*32 for MFMA
#define MM    33      // PCAP + 1
#define TT    16
#define NOUT  16      // OUT_CAPS

typedef _Float16 f16;
typedef f16 f16x8 __attribute__((ext_vector_type(8)));
typedef float f32x4 __attribute__((ext_vector_type(4)));

// ======================= k_pre: entmax (bisection) + leaf norm =======================
// entmax15(x): x' = (x - max)/2; solve sum(clip(x'-tau,0)^2) = 1 by bisection.
// blocks 0..527: blk = m*16+n; 16 entmax problems (one per t), one per 16-lane group.
// block 528: m1 masks (3 waves) + leaves (wave 3). block 529: m2 masks (3 waves).
__global__ __launch_bounds__(256) void k_pre(const float* __restrict__ route_w,
    const float* __restrict__ m1_w, const float* __restrict__ m2_w,
    const float* __restrict__ leaves,
    __half* __restrict__ w2t, float* __restrict__ mask1, float* __restrict__ mask2,
    float* __restrict__ lh_t){
  int blk = blockIdx.x, tid = threadIdx.x;
  if (blk < 528){
    const float* base = route_w + (size_t)blk*DD*16;   // [164][16] slab for (m,n)
    int l  = tid & 63;
    int t  = (tid>>6)*4 + (l&3);
    int lg = l>>2;                                     // d = lg + 16*i
    float v[11];
    float mx = -1e30f;
    #pragma unroll
    for (int i=0;i<11;++i){
      int d = lg + 16*i;
      v[i] = (d < DD) ? base[d*16 + t] : -1e30f;
      mx = fmaxf(mx, v[i]);
    }
    #pragma unroll
    for (int msk=4; msk<=32; msk<<=1) mx = fmaxf(mx, __shfl_xor(mx, msk));
    #pragma unroll
    for (int i=0;i<11;++i) v[i] = (v[i]-mx)*0.5f;
    float lo=-1.0f, hi=0.0f;
    for (int it=0; it<30; ++it){
      float mid = 0.5f*(lo+hi), g=0.0f;
      #pragma unroll
      for (int i=0;i<11;++i){ float tv = fmaxf(v[i]-mid, 0.0f); g += tv*tv; }
      #pragma unroll
      for (int msk=4; msk<=32; msk<<=1) g += __shfl_xor(g, msk);
      if (g > 1.0f) lo = mid; else hi = mid;           // uniform branch
    }
    float tau = 0.5f*(lo+hi);
    __half* wout = w2t + (size_t)(blk*16 + t)*DDP;
    #pragma unroll
    for (int i=0;i<12;++i){
      int d = lg + 16*i;
      if (d < DDP){
        float tv = 0.0f;
        if (i < 11 && d < DD){ tv = fmaxf(v[i]-tau, 0.0f); }
        wout[d] = __float2half(tv*tv);
      }
    }
  } else if (blk == 528){
    int wv = tid>>6, l = tid&63;
    if (wv < 3){
      float v0 = m1_w[wv*64 + l];
      float mx = v0;
      #pragma unroll
      for (int m=1;m<=32;m<<=1) mx = fmaxf(mx, __shfl_xor(mx,m));
      v0 = (v0-mx)*0.5f;
      float lo=-1.0f, hi=0.0f;
      for (int it=0;it<30;++it){
        float mid = 0.5f*(lo+hi);
        float tv = fmaxf(v0-mid, 0.0f);
        float g = tv*tv;
        #pragma unroll
        for (int m=1;m<=32;m<<=1) g += __shfl_xor(g,m);
        if (g > 1.0f) lo = mid; else hi = mid;
      }
      float tau = 0.5f*(lo+hi);
      float tv = fmaxf(v0-tau, 0.0f);
      mask1[wv*64 + l] = tv*tv;
    } else if (l < 32){
      int li = l;
      float s=0.0f;
      for (int t=0;t<TT;++t){ float vv=leaves[li*TT+t]; s+=vv*vv; }
      float dn = fmaxf(sqrtf(s), 1e-12f);
      for (int t=0;t<TT;++t) lh_t[t*32+li] = leaves[li*TT+t]/dn;  // transposed [t][l]
    }
  } else { // blk == 529: m2 masks, n=80
    int wv = tid>>6, l = tid&63;
    if (wv < 3){
      float v0 = m2_w[wv*80 + l];
      float v1 = (l < 16) ? m2_w[wv*80 + 64 + l] : -1e30f;
      float mx = fmaxf(v0, v1);
      #pragma unroll
      for (int m=1;m<=32;m<<=1) mx = fmaxf(mx, __shfl_xor(mx,m));
      v0 = (v0-mx)*0.5f; v1 = (v1-mx)*0.5f;
      float lo=-1.0f, hi=0.0f;
      for (int it=0;it<30;++it){
        float mid = 0.5f*(lo+hi);
        float t0 = fmaxf(v0-mid, 0.0f), t1 = fmaxf(v1-mid, 0.0f);
        float g = t0*t0 + t1*t1;
        #pragma unroll
        for (int m=1;m<=32;m<<=1) g += __shfl_xor(g,m);
        if (g > 1.0f) lo = mid; else hi = mid;
      }
      float tau = 0.5f*(lo+hi);
      float t0 = fmaxf(v0-tau, 0.0f);
      mask2[wv*80 + l] = t0*t0;
      if (l < 16){ float t1 = fmaxf(v1-tau, 0.0f); mask2[wv*80 + 64 + l] = t1*t1; }
    }
  }
}

// ======================= k_caps: encoder -> caps_t[m][bl][DDP] (f16, zero-padded) ====
__global__ __launch_bounds__(256) void k_caps(const float* __restrict__ x,
    const float* __restrict__ init_w, const float* __restrict__ init_b,
    const float* __restrict__ ln_g, const float* __restrict__ ln_b,
    const float* __restrict__ prim_fc, __half* __restrict__ caps_t, int b0, int nrows){
  int bl = blockIdx.x, b = b0 + bl, tid = threadIdx.x;
  __shared__ float f[DD], gs[DD], bs[DD], pfs[DD*32];
  if (tid < INDIM) f[tid] = x[(size_t)b*INDIM + tid];
  if (tid < DD){ gs[tid] = ln_g[tid]; bs[tid] = ln_b[tid]; }
  for (int i = tid; i < DD*32; i += 256) pfs[i] = prim_fc[i];
  __syncthreads();
  if (tid < INITD){
    float s = init_b[tid];
    for (int k=0;k<INDIM;++k) s += f[k]*init_w[tid*INDIM+k];
    f[INDIM+tid] = s;
  }
  __syncthreads();
  int w = tid>>6, lane = tid&63;
  for (int mi = w; mi < MM; mi += 4){
    float c[3]; float sum=0.0f, sq=0.0f;
    #pragma unroll
    for (int j=0;j<3;++j){
      int d = lane + 64*j;
      float v = 0.0f;
      if (d < DD) v = (mi < 32) ? f[d]*pfs[d*32+mi] : f[d];
      c[j] = v; sum += v; sq += v*v;
    }
    #pragma unroll
    for (int off=32; off; off>>=1){ sum += __shfl_xor(sum,off); sq += __shfl_xor(sq,off); }
    float mean = sum*(1.0f/DD);
    float var  = fmaxf(sq*(1.0f/DD) - mean*mean, 0.0f);
    float rstd = rsqrtf(var + 1e-5f);
    #pragma unroll
    for (int j=0;j<3;++j){
      int d = lane + 64*j;   // covers 0..191 exactly
      float o = (d < DD) ? ((c[j]-mean)*rstd*gs[d] + bs[d]) : 0.0f;
      caps_t[((size_t)mi*nrows + bl)*DDP + d] = __float2half(o);
    }
  }
}

// ======================= k_gemm_mfma: priors[bl][m][256] via 16x16x32 f16 MFMA =======
__global__ __launch_bounds__(256) void k_gemm_mfma(const f16* __restrict__ caps_t,
    const f16* __restrict__ w2t, __half* __restrict__ priors, int nrows){
  int m = blockIdx.y, b0 = blockIdx.x*64;
  int tid = threadIdx.x;
  int wave = tid>>6, lane = tid&63;
  __shared__ f16 Al[64][40];
  __shared__ f16 Wl[256][40];
  f32x4 acc[4][4];
  #pragma unroll
  for (int i=0;i<4;++i)
    #pragma unroll
    for (int j=0;j<4;++j) acc[i][j] = (f32x4){0.f,0.f,0.f,0.f};

  int ar = tid>>2, ac0 = (tid&3)*8;
  int rg = lane&15, kg = lane>>4;

  for (int kc = 0; kc < 6; ++kc){
    *(uint4*)&Al[ar][ac0] =
        *(const uint4*)&caps_t[((size_t)m*nrows + b0 + ar)*DDP + kc*32 + ac0];
    #pragma unroll
    for (int c=0;c<4;++c)
      *(uint4*)&Wl[tid][c*8] =
          *(const uint4*)&w2t[((size_t)m*256 + tid)*DDP + kc*32 + c*8];
    __syncthreads();
    f16x8 a[4], bf[4];
    #pragma unroll
    for (int i=0;i<4;++i) a[i]  = *(const f16x8*)&Al[i*16 + rg][kg*8];
    #pragma unroll
    for (int j=0;j<4;++j) bf[j] = *(const f16x8*)&Wl[wave*64 + j*16 + rg][kg*8];
    #pragma unroll
    for (int i=0;i<4;++i)
      #pragma unroll
      for (int j=0;j<4;++j)
        acc[i][j] = __builtin_amdgcn_mfma_f32_16x16x32_f16(a[i], bf[j], acc[i][j], 0, 0, 0);
    __syncthreads();
  }
  int rg4 = kg*4, cc = rg;
  #pragma unroll
  for (int i=0;i<4;++i)
    #pragma unroll
    for (int j=0;j<4;++j)
      #pragma unroll
      for (int r=0;r<4;++r)
        priors[(size_t)(b0 + i*16 + rg4 + r)*(MM*256) + m*256 + wave*64 + j*16 + cc]
            = __float2half(acc[i][j][r]);
}

// ======================= k_route: votes -> dis -> softmax -> hidden LN -> pred/hsel ===
// votesT[l][nl*33+m], stride 265 (9 mod 32, coprime -> conflict-free columns);
// vmean accumulated in-register, stored transposed vmeanT[l][nl].
__global__ __launch_bounds__(256) void k_route(const __half* __restrict__ priors,
    const float* __restrict__ lh_t, const float* __restrict__ thr_in,
    const float* __restrict__ cg, const float* __restrict__ cbv,
    const float* __restrict__ y, float* __restrict__ out_pred, float* __restrict__ hsel,
    int b0){
  int bl = blockIdx.x, b = b0 + bl, tid = threadIdx.x;
  __shared__ __half pr[MM*256];
  __shared__ float lhs[512];            // [t][l]
  __shared__ float votesT[32][265];     // [l][nl*33+m]
  __shared__ float vmeanT[32][9];       // [l][nl]
  __shared__ float wp[8*MM];
  __shared__ float hid[16*16];
  __shared__ float nrm[16];
  __shared__ float yw[4];
  {
    const unsigned* pbw = (const unsigned*)(priors + (size_t)bl*(MM*256));
    unsigned* prw = (unsigned*)pr;
    for (int i = tid; i < (MM*256)/2; i += 256) prw[i] = pbw[i];
  }
  for (int i = tid; i < 512; i += 256) lhs[i] = lh_t[i];
  if (tid < 4) yw[tid] = y[(size_t)b*4 + tid];
  __syncthreads();

  for (int nc = 0; nc < 2; ++nc){
    int nl = tid >> 5, l = tid & 31, n = nc*8 + nl;
    {
      float lh_reg[TT];
      #pragma unroll
      for (int t=0;t<TT;++t) lh_reg[t] = lhs[t*32+l];
      float vsum = 0.0f;
      for (int m=0;m<MM;++m){
        float s = 0.0f;
        const __half* p0 = &pr[m*256 + n*16];
        #pragma unroll
        for (int t=0;t<TT;++t) s += lh_reg[t]*__half2float(p0[t]);
        float v = 1.0f/(1.0f+__expf(-s));
        votesT[l][nl*MM+m] = v;
        vsum += v;
      }
      vmeanT[l][nl] = vsum*(1.0f/MM);
    }
    __syncthreads();
    // 8*MM = 264 > 256 threads — grid-stride required
    for (int i = tid; i < 8*MM; i += 256){
      int nl2 = i/MM, m = i%MM, n2 = nc*8 + nl2;
      float s = 0.0f;
      #pragma unroll 8
      for (int l2=0;l2<32;++l2){
        float dd = votesT[l2][i] - vmeanT[l2][nl2];
        s += dd*dd;
      }
      float dis = s*(1.0f/32);
      float th = thr_in[m*NOUT + n2];
      wp[nl2*MM+m] = fmaxf(th*th - dis, 0.0f);
    }
    __syncthreads();
    if (tid < 8){
      float mx = -1e30f;
      for (int m=0;m<MM;++m) mx = fmaxf(mx, wp[tid*MM+m]);
      float s = 0.0f;
      for (int m=0;m<MM;++m){ float e = __expf(wp[tid*MM+m]-mx); wp[tid*MM+m] = e; s += e; }
      float inv = 1.0f/s;
      for (int m=0;m<MM;++m) wp[tid*MM+m] *= inv;
    }
    __syncthreads();
    if (tid < 128){
      int nl3 = tid >> 4, t = tid & 15, n3 = nc*8 + nl3;
      float s = 0.0f;
      for (int m=0;m<MM;++m) s += wp[nl3*MM+m]*__half2float(pr[m*256 + n3*16 + t]);
      hid[n3*16+t] = s;
    }
    __syncthreads();
  }
  if (tid < 16){
    float s=0.0f, q=0.0f;
    for (int t=0;t<TT;++t){ float v=hid[tid*16+t]; s+=v; q+=v*v; }
    float mean = s*(1.0f/TT);
    float var  = fmaxf(q*(1.0f/TT)-mean*mean, 0.0f);
    float rstd = rsqrtf(var + 1e-5f);
    float nn = 0.0f;
    for (int t=0;t<TT;++t){
      float v = (hid[tid*16+t]-mean)*rstd*cg[t] + cbv[t];
      hid[tid*16+t] = v; nn += v*v;
    }
    nrm[tid] = sqrtf(nn);
  }
  __syncthreads();
  if (tid < 4)
    out_pred[(size_t)b*4 + tid] = nrm[tid*4+0]+nrm[tid*4+1]+nrm[tid*4+2]+nrm[tid*4+3];
  if (tid < 64){
    int s2 = tid >> 4, t = tid & 15;
    float v = 0.0f;
    #pragma unroll
    for (int c=0;c<4;++c) v += yw[c]*hid[(s2*4+c)*16 + t];
    hsel[(size_t)b*64 + tid] = v;
  }
}

// ======================= decoder (wide-grid) =========================================
__global__ __launch_bounds__(256) void k_h1(const float* __restrict__ hsel,
    const float* __restrict__ mask1, const float* __restrict__ fc1_w,
    const float* __restrict__ fc1_b, float* __restrict__ h1){
  int idx = blockIdx.x*256 + threadIdx.x;
  if (idx >= BATCH*96) return;
  int b = idx/96, j = idx%96, p = j>>5;
  float s = fc1_b[j];
  const float* hs = hsel + (size_t)b*64;
  const float* mk = mask1 + p*64;
  const float* wr = fc1_w + (size_t)j*64;
  for (int d=0; d<64; ++d) s += mk[d]*hs[d]*wr[d];
  h1[idx] = s;
}

__global__ __launch_bounds__(256) void k_stats(const float* __restrict__ h,
    float* __restrict__ stats, int F){
  int vb = blockIdx.x / F, j = blockIdx.x % F;
  float v = h[(size_t)(vb*256 + threadIdx.x)*F + j];
  float s = v, q = v*v;
  #pragma unroll
  for (int off=32; off; off>>=1){ s += __shfl_xor(s,off); q += __shfl_xor(q,off); }
  __shared__ float ps[4], pq[4];
  int w = threadIdx.x >> 6;
  if ((threadIdx.x & 63) == 0){ ps[w]=s; pq[w]=q; }
  __syncthreads();
  if (threadIdx.x == 0){
    float ss = ps[0]+ps[1]+ps[2]+ps[3];
    float qq = pq[0]+pq[1]+pq[2]+pq[3];
    float mean = ss*(1.0f/256);
    float var  = fmaxf(qq*(1.0f/256) - mean*mean, 0.0f);
    stats[(size_t)blockIdx.x*2]   = mean;
    stats[(size_t)blockIdx.x*2+1] = rsqrtf(var + 1e-5f);
  }
}

__global__ __launch_bounds__(192) void k_out1h2(const float* __restrict__ hsel,
    const float* __restrict__ h1, const float* __restrict__ stats1,
    const float* __restrict__ bn1g, const float* __restrict__ bn1b,
    const float* __restrict__ mask2, const float* __restrict__ fc2_w,
    const float* __restrict__ fc2_b, float* __restrict__ h2raw){
  int b = blockIdx.x, tid = threadIdx.x, vb = b >> 8;
  __shared__ float h2s[80];
  if (tid < 64) h2s[tid] = hsel[(size_t)b*64 + tid];
  if (tid < 16){
    float s = 0.0f;
    for (int p=0;p<3;++p){
      int ja = p*32 + tid, jb = ja + 16;
      float ha = (h1[(size_t)b*96+ja]-stats1[(vb*96+ja)*2])*stats1[(vb*96+ja)*2+1]*bn1g[ja] + bn1b[ja];
      float hb = (h1[(size_t)b*96+jb]-stats1[(vb*96+jb)*2])*stats1[(vb*96+jb)*2+1]*bn1g[jb] + bn1b[jb];
      float sg = 1.0f/(1.0f+__expf(-ha));
      s += fmaxf(sg*hb, 0.0f);
    }
    h2s[64+tid] = s;
  }
  __syncthreads();
  int p = tid >> 6;
  float s = fc2_b[tid];
  const float* mk = mask2 + p*80;
  const float* wr = fc2_w + (size_t)tid*80;
  for (int d=0; d<80; ++d) s += mk[d]*h2s[d]*wr[d];
  h2raw[(size_t)b*192 + tid] = s;
}

__global__ __launch_bounds__(128) void k_final(const float* __restrict__ h2raw,
    const float* __restrict__ stats2, const float* __restrict__ bn2g,
    const float* __restrict__ bn2b, const float* __restrict__ dec_w,
    const float* __restrict__ dec_b, float* __restrict__ out_rec){
  int b = blockIdx.x, tid = threadIdx.x, vb = b >> 8;
  __shared__ float o2[32];
  if (tid < 32){
    float s = 0.0f;
    for (int p=0;p<3;++p){
      int ja = p*64 + tid, jb = ja + 32;
      float ha = (h2raw[(size_t)b*192+ja]-stats2[(vb*192+ja)*2])*stats2[(vb*192+ja)*2+1]*bn2g[ja] + bn2b[ja];
      float hb = (h2raw[(size_t)b*192+jb]-stats2[(vb*192+jb)*2])*stats2[(vb*192+jb)*2+1]*bn2g[jb] + bn2b[jb];
      float sg = 1.0f/(1.0f+__expf(-ha));
      s += fmaxf(sg*hb, 0.0f);
    }
    o2[tid] = s;
  }
  __syncthreads();
  if (tid < INDIM){
    float r = dec_b[tid];
    #pragma unroll
    for (int o=0;o<32;++o) r += o2[o]*dec_w[tid*32+o];
    out_rec[(size_t)b*INDIM + tid] = r;
  }
}

// ======================= launch =======================
extern "C" void kernel_launch(void* const* d_in, const int* in_sizes, int n_in,
                              void* d_out, int out_size, void* d_ws, size_t ws_size,
                              hipStream_t stream){
  const float* x      = (const float*)d_in[0];
  const float* y      = (const float*)d_in[1];
  const float* init_w = (const float*)d_in[2];
  const float* init_b = (const float*)d_in[3];
  const float* eg     = (const float*)d_in[4];
  const float* ebv    = (const float*)d_in[5];
  const float* pf     = (const float*)d_in[6];
  const float* rw     = (const float*)d_in[7];
  const float* thr    = (const float*)d_in[8];
  const float* lv     = (const float*)d_in[9];
  const float* cg     = (const float*)d_in[10];
  const float* cbv    = (const float*)d_in[11];
  const float* m1w    = (const float*)d_in[12];
  const float* f1w    = (const float*)d_in[13];
  const float* f1b    = (const float*)d_in[14];
  const float* g1     = (const float*)d_in[15];
  const float* b1     = (const float*)d_in[16];
  const float* m2w    = (const float*)d_in[17];
  const float* f2w    = (const float*)d_in[18];
  const float* f2b    = (const float*)d_in[19];
  const float* g2     = (const float*)d_in[20];
  const float* b2v    = (const float*)d_in[21];
  const float* dw     = (const float*)d_in[22];
  const float* db     = (const float*)d_in[23];
  char* ws = (char*)d_ws;
  float* out = (float*)d_out;
  (void)in_sizes; (void)n_in; (void)out_size;

  // layout: [w2, caps, priors, m1, m2, lh, hsel, h1, s1, h2, s2]
  size_t offs[11];
  auto layout = [&](size_t nrows)->size_t{
    size_t o = 0; int i = 0;
    auto put = [&](size_t bytes){ offs[i++] = o; o = (o + bytes + 255) & ~(size_t)255; };
    put((size_t)MM*256*DDP*sizeof(__half));
    put((size_t)MM*nrows*DDP*sizeof(__half));
    put((size_t)nrows*MM*256*sizeof(__half));
    put(192*sizeof(float));
    put(240*sizeof(float));
    put(512*sizeof(float));
    put((size_t)BATCH*64*sizeof(float));
    put((size_t)BATCH*96*sizeof(float));
    put(16*96*2*sizeof(float));
    put((size_t)BATCH*192*sizeof(float));
    put(16*192*2*sizeof(float));
    return o;
  };
  int nrows = BATCH, nchunk = 1;
  if (layout(BATCH) > ws_size){ nrows = 1024; nchunk = 4; layout(1024); }
  __half* w2   = (__half*)(ws + offs[0]);
  __half* caps = (__half*)(ws + offs[1]);
  __half* pri  = (__half*)(ws + offs[2]);
  float*  m1   = (float*)(ws + offs[3]);
  float*  m2   = (float*)(ws + offs[4]);
  float*  lh   = (float*)(ws + offs[5]);
  float*  hsel = (float*)(ws + offs[6]);
  float*  h1   = (float*)(ws + offs[7]);
  float*  s1   = (float*)(ws + offs[8]);
  float*  h2   = (float*)(ws + offs[9]);
  float*  s2   = (float*)(ws + offs[10]);

  k_pre<<<dim3(530), dim3(256), 0, stream>>>(rw, m1w, m2w, lv, w2, m1, m2, lh);

  for (int c = 0; c < nchunk; ++c){
    int b0 = c*nrows;
    k_caps<<<dim3(nrows), dim3(256), 0, stream>>>(x, init_w, init_b, eg, ebv, pf,
        caps, b0, nrows);
    k_gemm_mfma<<<dim3(nrows/64, MM), dim3(256), 0, stream>>>(
        (const f16*)caps, (const f16*)w2, pri, nrows);
    k_route<<<dim3(nrows), dim3(256), 0, stream>>>(pri, lh, thr, cg, cbv, y,
        out, hsel, b0);
  }

  k_h1<<<dim3((BATCH*96)/256), dim3(256), 0, stream>>>(hsel, m1, f1w, f1b, h1);
  k_stats<<<dim3(16*96), dim3(256), 0, stream>>>(h1, s1, 96);
  k_out1h2<<<dim3(BATCH), dim3(192), 0, stream>>>(hsel, h1, s1, g1, b1,
      m2, f2w, f2b, h2);
  k_stats<<<dim3(16*192), dim3(256), 0, stream>>>(h2, s2, 192);
  k_final<<<dim3(BATCH), dim3(128), 0, stream>>>(h2, s2, g2, b2v, dw, db,
      out + (size_t)BATCH*NCLS);
}

// Round 10
// 414.260 us; speedup vs baseline: 1.9849x; 1.1311x over previous
//
#include <hip/hip_runtime.h>
#include <hip/hip_fp16.h>

#define BATCH 4096
#define NCLS  4
#define INDIM 100
#define INITD 64
#define DD    164     // IN_DIM + INIT_DIM
#define DDP   192     // K padded to 6*32 for MFMA
#define MM    33      // PCAP + 1
#define TT    16
#define NOUT  16      // OUT_CAPS

typedef _Float16 f16;
typedef f16 f16x8 __attribute__((ext_vector_type(8)));
typedef float f32x4 __attribute__((ext_vector_type(4)));

// ======================= k_pre: entmax (bisection) + leaf norm =======================
// entmax15(x): x' = (x - max)/2; solve sum(clip(x'-tau,0)^2) = 1 by bisection.
// blocks 0..527: blk = m*16+n; 16 entmax problems (one per t), one per 16-lane group.
// block 528: m1 masks (3 waves) + leaves (wave 3). block 529: m2 masks (3 waves).
__global__ __launch_bounds__(256) void k_pre(const float* __restrict__ route_w,
    const float* __restrict__ m1_w, const float* __restrict__ m2_w,
    const float* __restrict__ leaves,
    __half* __restrict__ w2t, float* __restrict__ mask1, float* __restrict__ mask2,
    float* __restrict__ lh_t){
  int blk = blockIdx.x, tid = threadIdx.x;
  if (blk < 528){
    const float* base = route_w + (size_t)blk*DD*16;   // [164][16] slab for (m,n)
    int l  = tid & 63;
    int t  = (tid>>6)*4 + (l&3);
    int lg = l>>2;                                     // d = lg + 16*i
    float v[11];
    float mx = -1e30f;
    #pragma unroll
    for (int i=0;i<11;++i){
      int d = lg + 16*i;
      v[i] = (d < DD) ? base[d*16 + t] : -1e30f;
      mx = fmaxf(mx, v[i]);
    }
    #pragma unroll
    for (int msk=4; msk<=32; msk<<=1) mx = fmaxf(mx, __shfl_xor(mx, msk));
    #pragma unroll
    for (int i=0;i<11;++i) v[i] = (v[i]-mx)*0.5f;
    float lo=-1.0f, hi=0.0f;
    for (int it=0; it<30; ++it){
      float mid = 0.5f*(lo+hi), g=0.0f;
      #pragma unroll
      for (int i=0;i<11;++i){ float tv = fmaxf(v[i]-mid, 0.0f); g += tv*tv; }
      #pragma unroll
      for (int msk=4; msk<=32; msk<<=1) g += __shfl_xor(g, msk);
      if (g > 1.0f) lo = mid; else hi = mid;           // uniform branch
    }
    float tau = 0.5f*(lo+hi);
    __half* wout = w2t + (size_t)(blk*16 + t)*DDP;
    #pragma unroll
    for (int i=0;i<12;++i){
      int d = lg + 16*i;
      if (d < DDP){
        float tv = 0.0f;
        if (i < 11 && d < DD){ tv = fmaxf(v[i]-tau, 0.0f); }
        wout[d] = __float2half(tv*tv);
      }
    }
  } else if (blk == 528){
    int wv = tid>>6, l = tid&63;
    if (wv < 3){
      float v0 = m1_w[wv*64 + l];
      float mx = v0;
      #pragma unroll
      for (int m=1;m<=32;m<<=1) mx = fmaxf(mx, __shfl_xor(mx,m));
      v0 = (v0-mx)*0.5f;
      float lo=-1.0f, hi=0.0f;
      for (int it=0;it<30;++it){
        float mid = 0.5f*(lo+hi);
        float tv = fmaxf(v0-mid, 0.0f);
        float g = tv*tv;
        #pragma unroll
        for (int m=1;m<=32;m<<=1) g += __shfl_xor(g,m);
        if (g > 1.0f) lo = mid; else hi = mid;
      }
      float tau = 0.5f*(lo+hi);
      float tv = fmaxf(v0-tau, 0.0f);
      mask1[wv*64 + l] = tv*tv;
    } else if (l < 32){
      int li = l;
      float s=0.0f;
      for (int t=0;t<TT;++t){ float vv=leaves[li*TT+t]; s+=vv*vv; }
      float dn = fmaxf(sqrtf(s), 1e-12f);
      for (int t=0;t<TT;++t) lh_t[t*32+li] = leaves[li*TT+t]/dn;  // transposed [t][l]
    }
  } else { // blk == 529: m2 masks, n=80
    int wv = tid>>6, l = tid&63;
    if (wv < 3){
      float v0 = m2_w[wv*80 + l];
      float v1 = (l < 16) ? m2_w[wv*80 + 64 + l] : -1e30f;
      float mx = fmaxf(v0, v1);
      #pragma unroll
      for (int m=1;m<=32;m<<=1) mx = fmaxf(mx, __shfl_xor(mx,m));
      v0 = (v0-mx)*0.5f; v1 = (v1-mx)*0.5f;
      float lo=-1.0f, hi=0.0f;
      for (int it=0;it<30;++it){
        float mid = 0.5f*(lo+hi);
        float t0 = fmaxf(v0-mid, 0.0f), t1 = fmaxf(v1-mid, 0.0f);
        float g = t0*t0 + t1*t1;
        #pragma unroll
        for (int m=1;m<=32;m<<=1) g += __shfl_xor(g,m);
        if (g > 1.0f) lo = mid; else hi = mid;
      }
      float tau = 0.5f*(lo+hi);
      float t0 = fmaxf(v0-tau, 0.0f);
      mask2[wv*80 + l] = t0*t0;
      if (l < 16){ float t1 = fmaxf(v1-tau, 0.0f); mask2[wv*80 + 64 + l] = t1*t1; }
    }
  }
}

// ======================= k_caps: encoder -> caps_t[m][bl][DDP] (f16, zero-padded) ====
__global__ __launch_bounds__(256) void k_caps(const float* __restrict__ x,
    const float* __restrict__ init_w, const float* __restrict__ init_b,
    const float* __restrict__ ln_g, const float* __restrict__ ln_b,
    const float* __restrict__ prim_fc, __half* __restrict__ caps_t, int b0, int nrows){
  int bl = blockIdx.x, b = b0 + bl, tid = threadIdx.x;
  __shared__ float f[DD], gs[DD], bs[DD], pfs[DD*32];
  if (tid < INDIM) f[tid] = x[(size_t)b*INDIM + tid];
  if (tid < DD){ gs[tid] = ln_g[tid]; bs[tid] = ln_b[tid]; }
  for (int i = tid; i < DD*32; i += 256) pfs[i] = prim_fc[i];
  __syncthreads();
  if (tid < INITD){
    float s = init_b[tid];
    for (int k=0;k<INDIM;++k) s += f[k]*init_w[tid*INDIM+k];
    f[INDIM+tid] = s;
  }
  __syncthreads();
  int w = tid>>6, lane = tid&63;
  for (int mi = w; mi < MM; mi += 4){
    float c[3]; float sum=0.0f, sq=0.0f;
    #pragma unroll
    for (int j=0;j<3;++j){
      int d = lane + 64*j;
      float v = 0.0f;
      if (d < DD) v = (mi < 32) ? f[d]*pfs[d*32+mi] : f[d];
      c[j] = v; sum += v; sq += v*v;
    }
    #pragma unroll
    for (int off=32; off; off>>=1){ sum += __shfl_xor(sum,off); sq += __shfl_xor(sq,off); }
    float mean = sum*(1.0f/DD);
    float var  = fmaxf(sq*(1.0f/DD) - mean*mean, 0.0f);
    float rstd = rsqrtf(var + 1e-5f);
    #pragma unroll
    for (int j=0;j<3;++j){
      int d = lane + 64*j;   // covers 0..191 exactly
      float o = (d < DD) ? ((c[j]-mean)*rstd*gs[d] + bs[d]) : 0.0f;
      caps_t[((size_t)mi*nrows + bl)*DDP + d] = __float2half(o);
    }
  }
}

// ======================= k_gemm_mfma: priors[bl][m][256] via 16x16x32 f16 MFMA =======
__global__ __launch_bounds__(256) void k_gemm_mfma(const f16* __restrict__ caps_t,
    const f16* __restrict__ w2t, __half* __restrict__ priors, int nrows){
  int m = blockIdx.y, b0 = blockIdx.x*64;
  int tid = threadIdx.x;
  int wave = tid>>6, lane = tid&63;
  __shared__ f16 Al[64][40];
  __shared__ f16 Wl[256][40];
  f32x4 acc[4][4];
  #pragma unroll
  for (int i=0;i<4;++i)
    #pragma unroll
    for (int j=0;j<4;++j) acc[i][j] = (f32x4){0.f,0.f,0.f,0.f};

  int ar = tid>>2, ac0 = (tid&3)*8;
  int rg = lane&15, kg = lane>>4;

  for (int kc = 0; kc < 6; ++kc){
    *(uint4*)&Al[ar][ac0] =
        *(const uint4*)&caps_t[((size_t)m*nrows + b0 + ar)*DDP + kc*32 + ac0];
    #pragma unroll
    for (int c=0;c<4;++c)
      *(uint4*)&Wl[tid][c*8] =
          *(const uint4*)&w2t[((size_t)m*256 + tid)*DDP + kc*32 + c*8];
    __syncthreads();
    f16x8 a[4], bf[4];
    #pragma unroll
    for (int i=0;i<4;++i) a[i]  = *(const f16x8*)&Al[i*16 + rg][kg*8];
    #pragma unroll
    for (int j=0;j<4;++j) bf[j] = *(const f16x8*)&Wl[wave*64 + j*16 + rg][kg*8];
    #pragma unroll
    for (int i=0;i<4;++i)
      #pragma unroll
      for (int j=0;j<4;++j)
        acc[i][j] = __builtin_amdgcn_mfma_f32_16x16x32_f16(a[i], bf[j], acc[i][j], 0, 0, 0);
    __syncthreads();
  }
  int rg4 = kg*4, cc = rg;
  #pragma unroll
  for (int i=0;i<4;++i)
    #pragma unroll
    for (int j=0;j<4;++j)
      #pragma unroll
      for (int r=0;r<4;++r)
        priors[(size_t)(b0 + i*16 + rg4 + r)*(MM*256) + m*256 + wave*64 + j*16 + cc]
            = __float2half(acc[i][j][r]);
}

// ======================= k_route: register-resident routing ==========================
// Thread (nl, l): n = nc*8+nl, votes v[m] in registers (static unroll), vmean per-thread,
// dis via 5-step shfl butterfly over the 32-l group, softmax in registers (redundant
// per lane), PV split across lane halves. No LDS for votes/dis/softmax, no barriers
// inside the nc loop.
__global__ __launch_bounds__(256) void k_route(const __half* __restrict__ priors,
    const float* __restrict__ lh_t, const float* __restrict__ thr_in,
    const float* __restrict__ cg, const float* __restrict__ cbv,
    const float* __restrict__ y, float* __restrict__ out_pred, float* __restrict__ hsel,
    int b0){
  int bl = blockIdx.x, b = b0 + bl, tid = threadIdx.x;
  __shared__ __half pr[MM*256];
  __shared__ float lhs[512];            // [t][l]
  __shared__ float th2s[MM*16];         // thread^2 [m][n]
  __shared__ float hid[16*16];
  __shared__ float nrm[16];
  __shared__ float yw[4];
  {
    const unsigned* pbw = (const unsigned*)(priors + (size_t)bl*(MM*256));
    unsigned* prw = (unsigned*)pr;
    for (int i = tid; i < (MM*256)/2; i += 256) prw[i] = pbw[i];
  }
  for (int i = tid; i < 512; i += 256) lhs[i] = lh_t[i];
  for (int i = tid; i < MM*16; i += 256){ float t = thr_in[i]; th2s[i] = t*t; }
  if (tid < 4) yw[tid] = y[(size_t)b*4 + tid];
  __syncthreads();

  int nl = tid >> 5, l = tid & 31;
  float lh_reg[TT];
  #pragma unroll
  for (int t=0;t<TT;++t) lh_reg[t] = lhs[t*32+l];

  for (int nc = 0; nc < 2; ++nc){
    int n = nc*8 + nl;
    float v[MM];
    float vsum = 0.0f;
    #pragma unroll
    for (int m=0;m<MM;++m){
      const f16* p0 = (const f16*)&pr[m*256 + n*16];
      f16x8 a0 = *(const f16x8*)p0;
      f16x8 a1 = *(const f16x8*)(p0+8);
      float s = 0.0f;
      #pragma unroll
      for (int t=0;t<8;++t) s += lh_reg[t]*(float)a0[t];
      #pragma unroll
      for (int t=0;t<8;++t) s += lh_reg[8+t]*(float)a1[t];
      float vv = 1.0f/(1.0f+__expf(-s));
      v[m] = vv; vsum += vv;
    }
    float mean_m = vsum*(1.0f/MM);
    // dis -> wgt (reuse v[]), track max for softmax
    float mx = -1e30f;
    #pragma unroll
    for (int m=0;m<MM;++m){
      float dd = v[m] - mean_m;
      float sq = dd*dd;
      #pragma unroll
      for (int msk=1; msk<=16; msk<<=1) sq += __shfl_xor(sq, msk);
      float wg = fmaxf(th2s[m*16+n] - sq*(1.0f/32), 0.0f);
      v[m] = wg; mx = fmaxf(mx, wg);
    }
    // softmax over m in registers (deferred normalization)
    float ssum = 0.0f;
    #pragma unroll
    for (int m=0;m<MM;++m){ float e = __expf(v[m]-mx); v[m] = e; ssum += e; }
    float inv = 1.0f/ssum;
    // PV: hidden[n][t] = inv * sum_m v[m]*pr[m][n*16+t]; split m over lane halves
    int t = l & 15;
    float h = 0.0f;
    if (l < 16){
      #pragma unroll
      for (int m=0;m<=16;++m) h += v[m]*(float)((const f16*)pr)[m*256 + n*16 + t];
    } else {
      #pragma unroll
      for (int m=17;m<MM;++m) h += v[m]*(float)((const f16*)pr)[m*256 + n*16 + t];
    }
    h += __shfl_xor(h, 16);
    if (l < 16) hid[n*16+t] = h*inv;
  }
  __syncthreads();
  if (tid < 16){
    float s=0.0f, q=0.0f;
    for (int t=0;t<TT;++t){ float v2=hid[tid*16+t]; s+=v2; q+=v2*v2; }
    float mean = s*(1.0f/TT);
    float var  = fmaxf(q*(1.0f/TT)-mean*mean, 0.0f);
    float rstd = rsqrtf(var + 1e-5f);
    float nn = 0.0f;
    for (int t=0;t<TT;++t){
      float v2 = (hid[tid*16+t]-mean)*rstd*cg[t] + cbv[t];
      hid[tid*16+t] = v2; nn += v2*v2;
    }
    nrm[tid] = sqrtf(nn);
  }
  __syncthreads();
  if (tid < 4)
    out_pred[(size_t)b*4 + tid] = nrm[tid*4+0]+nrm[tid*4+1]+nrm[tid*4+2]+nrm[tid*4+3];
  if (tid < 64){
    int s2 = tid >> 4, t = tid & 15;
    float v2 = 0.0f;
    #pragma unroll
    for (int c=0;c<4;++c) v2 += yw[c]*hid[(s2*4+c)*16 + t];
    hsel[(size_t)b*64 + tid] = v2;
  }
}

// ======================= decoder (wide-grid) =========================================
__global__ __launch_bounds__(256) void k_h1(const float* __restrict__ hsel,
    const float* __restrict__ mask1, const float* __restrict__ fc1_w,
    const float* __restrict__ fc1_b, float* __restrict__ h1){
  int idx = blockIdx.x*256 + threadIdx.x;
  if (idx >= BATCH*96) return;
  int b = idx/96, j = idx%96, p = j>>5;
  float s = fc1_b[j];
  const float* hs = hsel + (size_t)b*64;
  const float* mk = mask1 + p*64;
  const float* wr = fc1_w + (size_t)j*64;
  for (int d=0; d<64; ++d) s += mk[d]*hs[d]*wr[d];
  h1[idx] = s;
}

__global__ __launch_bounds__(256) void k_stats(const float* __restrict__ h,
    float* __restrict__ stats, int F){
  int vb = blockIdx.x / F, j = blockIdx.x % F;
  float v = h[(size_t)(vb*256 + threadIdx.x)*F + j];
  float s = v, q = v*v;
  #pragma unroll
  for (int off=32; off; off>>=1){ s += __shfl_xor(s,off); q += __shfl_xor(q,off); }
  __shared__ float ps[4], pq[4];
  int w = threadIdx.x >> 6;
  if ((threadIdx.x & 63) == 0){ ps[w]=s; pq[w]=q; }
  __syncthreads();
  if (threadIdx.x == 0){
    float ss = ps[0]+ps[1]+ps[2]+ps[3];
    float qq = pq[0]+pq[1]+pq[2]+pq[3];
    float mean = ss*(1.0f/256);
    float var  = fmaxf(qq*(1.0f/256) - mean*mean, 0.0f);
    stats[(size_t)blockIdx.x*2]   = mean;
    stats[(size_t)blockIdx.x*2+1] = rsqrtf(var + 1e-5f);
  }
}

__global__ __launch_bounds__(192) void k_out1h2(const float* __restrict__ hsel,
    const float* __restrict__ h1, const float* __restrict__ stats1,
    const float* __restrict__ bn1g, const float* __restrict__ bn1b,
    const float* __restrict__ mask2, const float* __restrict__ fc2_w,
    const float* __restrict__ fc2_b, float* __restrict__ h2raw){
  int b = blockIdx.x, tid = threadIdx.x, vb = b >> 8;
  __shared__ float h2s[80];
  if (tid < 64) h2s[tid] = hsel[(size_t)b*64 + tid];
  if (tid < 16){
    float s = 0.0f;
    for (int p=0;p<3;++p){
      int ja = p*32 + tid, jb = ja + 16;
      float ha = (h1[(size_t)b*96+ja]-stats1[(vb*96+ja)*2])*stats1[(vb*96+ja)*2+1]*bn1g[ja] + bn1b[ja];
      float hb = (h1[(size_t)b*96+jb]-stats1[(vb*96+jb)*2])*stats1[(vb*96+jb)*2+1]*bn1g[jb] + bn1b[jb];
      float sg = 1.0f/(1.0f+__expf(-ha));
      s += fmaxf(sg*hb, 0.0f);
    }
    h2s[64+tid] = s;
  }
  __syncthreads();
  int p = tid >> 6;
  float s = fc2_b[tid];
  const float* mk = mask2 + p*80;
  const float* wr = fc2_w + (size_t)tid*80;
  for (int d=0; d<80; ++d) s += mk[d]*h2s[d]*wr[d];
  h2raw[(size_t)b*192 + tid] = s;
}

__global__ __launch_bounds__(128) void k_final(const float* __restrict__ h2raw,
    const float* __restrict__ stats2, const float* __restrict__ bn2g,
    const float* __restrict__ bn2b, const float* __restrict__ dec_w,
    const float* __restrict__ dec_b, float* __restrict__ out_rec){
  int b = blockIdx.x, tid = threadIdx.x, vb = b >> 8;
  __shared__ float o2[32];
  if (tid < 32){
    float s = 0.0f;
    for (int p=0;p<3;++p){
      int ja = p*64 + tid, jb = ja + 32;
      float ha = (h2raw[(size_t)b*192+ja]-stats2[(vb*192+ja)*2])*stats2[(vb*192+ja)*2+1]*bn2g[ja] + bn2b[ja];
      float hb = (h2raw[(size_t)b*192+jb]-stats2[(vb*192+jb)*2])*stats2[(vb*192+jb)*2+1]*bn2g[jb] + bn2b[jb];
      float sg = 1.0f/(1.0f+__expf(-ha));
      s += fmaxf(sg*hb, 0.0f);
    }
    o2[tid] = s;
  }
  __syncthreads();
  if (tid < INDIM){
    float r = dec_b[tid];
    #pragma unroll
    for (int o=0;o<32;++o) r += o2[o]*dec_w[tid*32+o];
    out_rec[(size_t)b*INDIM + tid] = r;
  }
}

// ======================= launch =======================
extern "C" void kernel_launch(void* const* d_in, const int* in_sizes, int n_in,
                              void* d_out, int out_size, void* d_ws, size_t ws_size,
                              hipStream_t stream){
  const float* x      = (const float*)d_in[0];
  const float* y      = (const float*)d_in[1];
  const float* init_w = (const float*)d_in[2];
  const float* init_b = (const float*)d_in[3];
  const float* eg     = (const float*)d_in[4];
  const float* ebv    = (const float*)d_in[5];
  const float* pf     = (const float*)d_in[6];
  const float* rw     = (const float*)d_in[7];
  const float* thr    = (const float*)d_in[8];
  const float* lv     = (const float*)d_in[9];
  const float* cg     = (const float*)d_in[10];
  const float* cbv    = (const float*)d_in[11];
  const float* m1w    = (const float*)d_in[12];
  const float* f1w    = (const float*)d_in[13];
  const float* f1b    = (const float*)d_in[14];
  const float* g1     = (const float*)d_in[15];
  const float* b1     = (const float*)d_in[16];
  const float* m2w    = (const float*)d_in[17];
  const float* f2w    = (const float*)d_in[18];
  const float* f2b    = (const float*)d_in[19];
  const float* g2     = (const float*)d_in[20];
  const float* b2v    = (const float*)d_in[21];
  const float* dw     = (const float*)d_in[22];
  const float* db     = (const float*)d_in[23];
  char* ws = (char*)d_ws;
  float* out = (float*)d_out;
  (void)in_sizes; (void)n_in; (void)out_size;

  // layout: [w2, caps, priors, m1, m2, lh, hsel, h1, s1, h2, s2]
  size_t offs[11];
  auto layout = [&](size_t nrows)->size_t{
    size_t o = 0; int i = 0;
    auto put = [&](size_t bytes){ offs[i++] = o; o = (o + bytes + 255) & ~(size_t)255; };
    put((size_t)MM*256*DDP*sizeof(__half));
    put((size_t)MM*nrows*DDP*sizeof(__half));
    put((size_t)nrows*MM*256*sizeof(__half));
    put(192*sizeof(float));
    put(240*sizeof(float));
    put(512*sizeof(float));
    put((size_t)BATCH*64*sizeof(float));
    put((size_t)BATCH*96*sizeof(float));
    put(16*96*2*sizeof(float));
    put((size_t)BATCH*192*sizeof(float));
    put(16*192*2*sizeof(float));
    return o;
  };
  int nrows = BATCH, nchunk = 1;
  if (layout(BATCH) > ws_size){ nrows = 1024; nchunk = 4; layout(1024); }
  __half* w2   = (__half*)(ws + offs[0]);
  __half* caps = (__half*)(ws + offs[1]);
  __half* pri  = (__half*)(ws + offs[2]);
  float*  m1   = (float*)(ws + offs[3]);
  float*  m2   = (float*)(ws + offs[4]);
  float*  lh   = (float*)(ws + offs[5]);
  float*  hsel = (float*)(ws + offs[6]);
  float*  h1   = (float*)(ws + offs[7]);
  float*  s1   = (float*)(ws + offs[8]);
  float*  h2   = (float*)(ws + offs[9]);
  float*  s2   = (float*)(ws + offs[10]);

  k_pre<<<dim3(530), dim3(256), 0, stream>>>(rw, m1w, m2w, lv, w2, m1, m2, lh);

  for (int c = 0; c < nchunk; ++c){
    int b0 = c*nrows;
    k_caps<<<dim3(nrows), dim3(256), 0, stream>>>(x, init_w, init_b, eg, ebv, pf,
        caps, b0, nrows);
    k_gemm_mfma<<<dim3(nrows/64, MM), dim3(256), 0, stream>>>(
        (const f16*)caps, (const f16*)w2, pri, nrows);
    k_route<<<dim3(nrows), dim3(256), 0, stream>>>(pri, lh, thr, cg, cbv, y,
        out, hsel, b0);
  }

  k_h1<<<dim3((BATCH*96)/256), dim3(256), 0, stream>>>(hsel, m1, f1w, f1b, h1);
  k_stats<<<dim3(16*96), dim3(256), 0, stream>>>(h1, s1, 96);
  k_out1h2<<<dim3(BATCH), dim3(192), 0, stream>>>(hsel, h1, s1, g1, b1,
      m2, f2w, f2b, h2);
  k_stats<<<dim3(16*192), dim3(256), 0, stream>>>(h2, s2, 192);
  k_final<<<dim3(BATCH), dim3(128), 0, stream>>>(h2, s2, g2, b2v, dw, db,
      out + (size_t)BATCH*NCLS);
}

// Round 11
// 414.005 us; speedup vs baseline: 1.9861x; 1.0006x over previous
//
#include <hip/hip_runtime.h>
#include <hip/hip_fp16.h>

#define BATCH 4096
#define NCLS  4
#define INDIM 100
#define INITD 64
#define DD    164     // IN_DIM + INIT_DIM
#define DDP   192     // K padded to 6*32 for MFMA
#define MM    33      // PCAP + 1
#define TT    16
#define NOUT  16      // OUT_CAPS

typedef _Float16 f16;
typedef f16 f16x8 __attribute__((ext_vector_type(8)));
typedef f16 f16x2 __attribute__((ext_vector_type(2)));
typedef float f32x4 __attribute__((ext_vector_type(4)));

// ======================= k_pre: entmax (bisection) + leaf norm =======================
// entmax15(x): x' = (x - max)/2; solve sum(clip(x'-tau,0)^2) = 1 by bisection.
// blocks 0..527: blk = m*16+n; 16 entmax problems (one per t), one per 16-lane group.
// block 528: m1 masks (3 waves) + leaves (wave 3). block 529: m2 masks (3 waves).
__global__ __launch_bounds__(256) void k_pre(const float* __restrict__ route_w,
    const float* __restrict__ m1_w, const float* __restrict__ m2_w,
    const float* __restrict__ leaves,
    __half* __restrict__ w2t, float* __restrict__ mask1, float* __restrict__ mask2,
    float* __restrict__ lh_t){
  int blk = blockIdx.x, tid = threadIdx.x;
  if (blk < 528){
    const float* base = route_w + (size_t)blk*DD*16;   // [164][16] slab for (m,n)
    int l  = tid & 63;
    int t  = (tid>>6)*4 + (l&3);
    int lg = l>>2;                                     // d = lg + 16*i
    float v[11];
    float mx = -1e30f;
    #pragma unroll
    for (int i=0;i<11;++i){
      int d = lg + 16*i;
      v[i] = (d < DD) ? base[d*16 + t] : -1e30f;
      mx = fmaxf(mx, v[i]);
    }
    #pragma unroll
    for (int msk=4; msk<=32; msk<<=1) mx = fmaxf(mx, __shfl_xor(mx, msk));
    #pragma unroll
    for (int i=0;i<11;++i) v[i] = (v[i]-mx)*0.5f;
    float lo=-1.0f, hi=0.0f;
    for (int it=0; it<30; ++it){
      float mid = 0.5f*(lo+hi), g=0.0f;
      #pragma unroll
      for (int i=0;i<11;++i){ float tv = fmaxf(v[i]-mid, 0.0f); g += tv*tv; }
      #pragma unroll
      for (int msk=4; msk<=32; msk<<=1) g += __shfl_xor(g, msk);
      if (g > 1.0f) lo = mid; else hi = mid;           // uniform branch
    }
    float tau = 0.5f*(lo+hi);
    __half* wout = w2t + (size_t)(blk*16 + t)*DDP;
    #pragma unroll
    for (int i=0;i<12;++i){
      int d = lg + 16*i;
      if (d < DDP){
        float tv = 0.0f;
        if (i < 11 && d < DD){ tv = fmaxf(v[i]-tau, 0.0f); }
        wout[d] = __float2half(tv*tv);
      }
    }
  } else if (blk == 528){
    int wv = tid>>6, l = tid&63;
    if (wv < 3){
      float v0 = m1_w[wv*64 + l];
      float mx = v0;
      #pragma unroll
      for (int m=1;m<=32;m<<=1) mx = fmaxf(mx, __shfl_xor(mx,m));
      v0 = (v0-mx)*0.5f;
      float lo=-1.0f, hi=0.0f;
      for (int it=0;it<30;++it){
        float mid = 0.5f*(lo+hi);
        float tv = fmaxf(v0-mid, 0.0f);
        float g = tv*tv;
        #pragma unroll
        for (int m=1;m<=32;m<<=1) g += __shfl_xor(g,m);
        if (g > 1.0f) lo = mid; else hi = mid;
      }
      float tau = 0.5f*(lo+hi);
      float tv = fmaxf(v0-tau, 0.0f);
      mask1[wv*64 + l] = tv*tv;
    } else if (l < 32){
      int li = l;
      float s=0.0f;
      for (int t=0;t<TT;++t){ float vv=leaves[li*TT+t]; s+=vv*vv; }
      float dn = fmaxf(sqrtf(s), 1e-12f);
      for (int t=0;t<TT;++t) lh_t[t*32+li] = leaves[li*TT+t]/dn;  // transposed [t][l]
    }
  } else { // blk == 529: m2 masks, n=80
    int wv = tid>>6, l = tid&63;
    if (wv < 3){
      float v0 = m2_w[wv*80 + l];
      float v1 = (l < 16) ? m2_w[wv*80 + 64 + l] : -1e30f;
      float mx = fmaxf(v0, v1);
      #pragma unroll
      for (int m=1;m<=32;m<<=1) mx = fmaxf(mx, __shfl_xor(mx,m));
      v0 = (v0-mx)*0.5f; v1 = (v1-mx)*0.5f;
      float lo=-1.0f, hi=0.0f;
      for (int it=0;it<30;++it){
        float mid = 0.5f*(lo+hi);
        float t0 = fmaxf(v0-mid, 0.0f), t1 = fmaxf(v1-mid, 0.0f);
        float g = t0*t0 + t1*t1;
        #pragma unroll
        for (int m=1;m<=32;m<<=1) g += __shfl_xor(g,m);
        if (g > 1.0f) lo = mid; else hi = mid;
      }
      float tau = 0.5f*(lo+hi);
      float t0 = fmaxf(v0-tau, 0.0f);
      mask2[wv*80 + l] = t0*t0;
      if (l < 16){ float t1 = fmaxf(v1-tau, 0.0f); mask2[wv*80 + 64 + l] = t1*t1; }
    }
  }
}

// ======================= k_caps: encoder -> caps_t[m][bl][DDP] (f16, zero-padded) ====
__global__ __launch_bounds__(256) void k_caps(const float* __restrict__ x,
    const float* __restrict__ init_w, const float* __restrict__ init_b,
    const float* __restrict__ ln_g, const float* __restrict__ ln_b,
    const float* __restrict__ prim_fc, __half* __restrict__ caps_t, int b0, int nrows){
  int bl = blockIdx.x, b = b0 + bl, tid = threadIdx.x;
  __shared__ float f[DD], gs[DD], bs[DD], pfs[DD*32];
  if (tid < INDIM) f[tid] = x[(size_t)b*INDIM + tid];
  if (tid < DD){ gs[tid] = ln_g[tid]; bs[tid] = ln_b[tid]; }
  for (int i = tid; i < DD*32; i += 256) pfs[i] = prim_fc[i];
  __syncthreads();
  if (tid < INITD){
    float s = init_b[tid];
    for (int k=0;k<INDIM;++k) s += f[k]*init_w[tid*INDIM+k];
    f[INDIM+tid] = s;
  }
  __syncthreads();
  int w = tid>>6, lane = tid&63;
  for (int mi = w; mi < MM; mi += 4){
    float c[3]; float sum=0.0f, sq=0.0f;
    #pragma unroll
    for (int j=0;j<3;++j){
      int d = lane + 64*j;
      float v = 0.0f;
      if (d < DD) v = (mi < 32) ? f[d]*pfs[d*32+mi] : f[d];
      c[j] = v; sum += v; sq += v*v;
    }
    #pragma unroll
    for (int off=32; off; off>>=1){ sum += __shfl_xor(sum,off); sq += __shfl_xor(sq,off); }
    float mean = sum*(1.0f/DD);
    float var  = fmaxf(sq*(1.0f/DD) - mean*mean, 0.0f);
    float rstd = rsqrtf(var + 1e-5f);
    #pragma unroll
    for (int j=0;j<3;++j){
      int d = lane + 64*j;   // covers 0..191 exactly
      float o = (d < DD) ? ((c[j]-mean)*rstd*gs[d] + bs[d]) : 0.0f;
      caps_t[((size_t)mi*nrows + bl)*DDP + d] = __float2half(o);
    }
  }
}

// ======================= k_gemm_mfma: priors[bl][m][256] via 16x16x32 f16 MFMA =======
__global__ __launch_bounds__(256) void k_gemm_mfma(const f16* __restrict__ caps_t,
    const f16* __restrict__ w2t, __half* __restrict__ priors, int nrows){
  int m = blockIdx.y, b0 = blockIdx.x*64;
  int tid = threadIdx.x;
  int wave = tid>>6, lane = tid&63;
  __shared__ f16 Al[64][40];
  __shared__ f16 Wl[256][40];
  f32x4 acc[4][4];
  #pragma unroll
  for (int i=0;i<4;++i)
    #pragma unroll
    for (int j=0;j<4;++j) acc[i][j] = (f32x4){0.f,0.f,0.f,0.f};

  int ar = tid>>2, ac0 = (tid&3)*8;
  int rg = lane&15, kg = lane>>4;

  for (int kc = 0; kc < 6; ++kc){
    *(uint4*)&Al[ar][ac0] =
        *(const uint4*)&caps_t[((size_t)m*nrows + b0 + ar)*DDP + kc*32 + ac0];
    #pragma unroll
    for (int c=0;c<4;++c)
      *(uint4*)&Wl[tid][c*8] =
          *(const uint4*)&w2t[((size_t)m*256 + tid)*DDP + kc*32 + c*8];
    __syncthreads();
    f16x8 a[4], bf[4];
    #pragma unroll
    for (int i=0;i<4;++i) a[i]  = *(const f16x8*)&Al[i*16 + rg][kg*8];
    #pragma unroll
    for (int j=0;j<4;++j) bf[j] = *(const f16x8*)&Wl[wave*64 + j*16 + rg][kg*8];
    #pragma unroll
    for (int i=0;i<4;++i)
      #pragma unroll
      for (int j=0;j<4;++j)
        acc[i][j] = __builtin_amdgcn_mfma_f32_16x16x32_f16(a[i], bf[j], acc[i][j], 0, 0, 0);
    __syncthreads();
  }
  int rg4 = kg*4, cc = rg;
  #pragma unroll
  for (int i=0;i<4;++i)
    #pragma unroll
    for (int j=0;j<4;++j)
      #pragma unroll
      for (int r=0;r<4;++r)
        priors[(size_t)(b0 + i*16 + rg4 + r)*(MM*256) + m*256 + wave*64 + j*16 + cc]
            = __float2half(acc[i][j][r]);
}

// ======================= k_route: register-resident routing (dot2) ===================
// Thread (nl, l): n = nc*8+nl, votes v[m] in registers via v_dot2_f32_f16,
// dis via shfl butterfly, softmax in registers WITHOUT max-subtraction
// (wgt in [0,1): th ~ U[0,1) so th^2 < 1, dis >= 0 -> exp is safe).
__global__ __launch_bounds__(256) void k_route(const __half* __restrict__ priors,
    const float* __restrict__ lh_t, const float* __restrict__ thr_in,
    const float* __restrict__ cg, const float* __restrict__ cbv,
    const float* __restrict__ y, float* __restrict__ out_pred, float* __restrict__ hsel,
    int b0){
  int bl = blockIdx.x, b = b0 + bl, tid = threadIdx.x;
  __shared__ __half pr[MM*256];
  __shared__ float lhs[512];            // [t][l]
  __shared__ float th2s[MM*16];         // thread^2 [m][n]
  __shared__ float hid[16*16];
  __shared__ float nrm[16];
  __shared__ float yw[4];
  {
    const unsigned* pbw = (const unsigned*)(priors + (size_t)bl*(MM*256));
    unsigned* prw = (unsigned*)pr;
    for (int i = tid; i < (MM*256)/2; i += 256) prw[i] = pbw[i];
  }
  for (int i = tid; i < 512; i += 256) lhs[i] = lh_t[i];
  for (int i = tid; i < MM*16; i += 256){ float t = thr_in[i]; th2s[i] = t*t; }
  if (tid < 4) yw[tid] = y[(size_t)b*4 + tid];
  __syncthreads();

  int nl = tid >> 5, l = tid & 31;
  f16x2 lh2[8];
  #pragma unroll
  for (int i=0;i<8;++i){
    lh2[i][0] = (f16)lhs[(2*i)*32+l];
    lh2[i][1] = (f16)lhs[(2*i+1)*32+l];
  }

  for (int nc = 0; nc < 2; ++nc){
    int n = nc*8 + nl;
    float v[MM];
    float vsum = 0.0f;
    #pragma unroll
    for (int m=0;m<MM;++m){
      const f16x2* p2 = (const f16x2*)&pr[m*256 + n*16];
      float s = 0.0f;
#if __has_builtin(__builtin_amdgcn_fdot2)
      #pragma unroll
      for (int i=0;i<8;++i) s = __builtin_amdgcn_fdot2(p2[i], lh2[i], s, false);
#else
      #pragma unroll
      for (int i=0;i<8;++i){
        f16x2 a = p2[i];
        s += (float)a[0]*(float)lh2[i][0] + (float)a[1]*(float)lh2[i][1];
      }
#endif
      float vv = 1.0f/(1.0f+__expf(-s));
      v[m] = vv; vsum += vv;
    }
    float mean_m = vsum*(1.0f/MM);
    // dis -> wgt (reuse v[])
    #pragma unroll
    for (int m=0;m<MM;++m){
      float dd = v[m] - mean_m;
      float sq = dd*dd;
      #pragma unroll
      for (int msk=1; msk<=16; msk<<=1) sq += __shfl_xor(sq, msk);
      v[m] = fmaxf(th2s[m*16+n] - sq*(1.0f/32), 0.0f);   // wgt in [0,1)
    }
    // softmax over m in registers, no max-subtraction needed
    float ssum = 0.0f;
    #pragma unroll
    for (int m=0;m<MM;++m){ float e = __expf(v[m]); v[m] = e; ssum += e; }
    float inv = 1.0f/ssum;
    // PV: hidden[n][t] = inv * sum_m v[m]*pr[m][n*16+t]; split m over lane halves
    int t = l & 15;
    float h = 0.0f;
    if (l < 16){
      #pragma unroll
      for (int m=0;m<=16;++m) h += v[m]*(float)((const f16*)pr)[m*256 + n*16 + t];
    } else {
      #pragma unroll
      for (int m=17;m<MM;++m) h += v[m]*(float)((const f16*)pr)[m*256 + n*16 + t];
    }
    h += __shfl_xor(h, 16);
    if (l < 16) hid[n*16+t] = h*inv;
  }
  __syncthreads();
  if (tid < 16){
    float s=0.0f, q=0.0f;
    for (int t=0;t<TT;++t){ float v2=hid[tid*16+t]; s+=v2; q+=v2*v2; }
    float mean = s*(1.0f/TT);
    float var  = fmaxf(q*(1.0f/TT)-mean*mean, 0.0f);
    float rstd = rsqrtf(var + 1e-5f);
    float nn = 0.0f;
    for (int t=0;t<TT;++t){
      float v2 = (hid[tid*16+t]-mean)*rstd*cg[t] + cbv[t];
      hid[tid*16+t] = v2; nn += v2*v2;
    }
    nrm[tid] = sqrtf(nn);
  }
  __syncthreads();
  if (tid < 4)
    out_pred[(size_t)b*4 + tid] = nrm[tid*4+0]+nrm[tid*4+1]+nrm[tid*4+2]+nrm[tid*4+3];
  if (tid < 64){
    int s2 = tid >> 4, t = tid & 15;
    float v2 = 0.0f;
    #pragma unroll
    for (int c=0;c<4;++c) v2 += yw[c]*hid[(s2*4+c)*16 + t];
    hsel[(size_t)b*64 + tid] = v2;
  }
}

// ======================= decoder (wide-grid) =========================================
__global__ __launch_bounds__(256) void k_h1(const float* __restrict__ hsel,
    const float* __restrict__ mask1, const float* __restrict__ fc1_w,
    const float* __restrict__ fc1_b, float* __restrict__ h1){
  int idx = blockIdx.x*256 + threadIdx.x;
  if (idx >= BATCH*96) return;
  int b = idx/96, j = idx%96, p = j>>5;
  float s = fc1_b[j];
  const float* hs = hsel + (size_t)b*64;
  const float* mk = mask1 + p*64;
  const float* wr = fc1_w + (size_t)j*64;
  for (int d=0; d<64; ++d) s += mk[d]*hs[d]*wr[d];
  h1[idx] = s;
}

__global__ __launch_bounds__(256) void k_stats(const float* __restrict__ h,
    float* __restrict__ stats, int F){
  int vb = blockIdx.x / F, j = blockIdx.x % F;
  float v = h[(size_t)(vb*256 + threadIdx.x)*F + j];
  float s = v, q = v*v;
  #pragma unroll
  for (int off=32; off; off>>=1){ s += __shfl_xor(s,off); q += __shfl_xor(q,off); }
  __shared__ float ps[4], pq[4];
  int w = threadIdx.x >> 6;
  if ((threadIdx.x & 63) == 0){ ps[w]=s; pq[w]=q; }
  __syncthreads();
  if (threadIdx.x == 0){
    float ss = ps[0]+ps[1]+ps[2]+ps[3];
    float qq = pq[0]+pq[1]+pq[2]+pq[3];
    float mean = ss*(1.0f/256);
    float var  = fmaxf(qq*(1.0f/256) - mean*mean, 0.0f);
    stats[(size_t)blockIdx.x*2]   = mean;
    stats[(size_t)blockIdx.x*2+1] = rsqrtf(var + 1e-5f);
  }
}

__global__ __launch_bounds__(192) void k_out1h2(const float* __restrict__ hsel,
    const float* __restrict__ h1, const float* __restrict__ stats1,
    const float* __restrict__ bn1g, const float* __restrict__ bn1b,
    const float* __restrict__ mask2, const float* __restrict__ fc2_w,
    const float* __restrict__ fc2_b, float* __restrict__ h2raw){
  int b = blockIdx.x, tid = threadIdx.x, vb = b >> 8;
  __shared__ float h2s[80];
  if (tid < 64) h2s[tid] = hsel[(size_t)b*64 + tid];
  if (tid < 16){
    float s = 0.0f;
    for (int p=0;p<3;++p){
      int ja = p*32 + tid, jb = ja + 16;
      float ha = (h1[(size_t)b*96+ja]-stats1[(vb*96+ja)*2])*stats1[(vb*96+ja)*2+1]*bn1g[ja] + bn1b[ja];
      float hb = (h1[(size_t)b*96+jb]-stats1[(vb*96+jb)*2])*stats1[(vb*96+jb)*2+1]*bn1g[jb] + bn1b[jb];
      float sg = 1.0f/(1.0f+__expf(-ha));
      s += fmaxf(sg*hb, 0.0f);
    }
    h2s[64+tid] = s;
  }
  __syncthreads();
  int p = tid >> 6;
  float s = fc2_b[tid];
  const float* mk = mask2 + p*80;
  const float* wr = fc2_w + (size_t)tid*80;
  for (int d=0; d<80; ++d) s += mk[d]*h2s[d]*wr[d];
  h2raw[(size_t)b*192 + tid] = s;
}

__global__ __launch_bounds__(128) void k_final(const float* __restrict__ h2raw,
    const float* __restrict__ stats2, const float* __restrict__ bn2g,
    const float* __restrict__ bn2b, const float* __restrict__ dec_w,
    const float* __restrict__ dec_b, float* __restrict__ out_rec){
  int b = blockIdx.x, tid = threadIdx.x, vb = b >> 8;
  __shared__ float o2[32];
  if (tid < 32){
    float s = 0.0f;
    for (int p=0;p<3;++p){
      int ja = p*64 + tid, jb = ja + 32;
      float ha = (h2raw[(size_t)b*192+ja]-stats2[(vb*192+ja)*2])*stats2[(vb*192+ja)*2+1]*bn2g[ja] + bn2b[ja];
      float hb = (h2raw[(size_t)b*192+jb]-stats2[(vb*192+jb)*2])*stats2[(vb*192+jb)*2+1]*bn2g[jb] + bn2b[jb];
      float sg = 1.0f/(1.0f+__expf(-ha));
      s += fmaxf(sg*hb, 0.0f);
    }
    o2[tid] = s;
  }
  __syncthreads();
  if (tid < INDIM){
    float r = dec_b[tid];
    #pragma unroll
    for (int o=0;o<32;++o) r += o2[o]*dec_w[tid*32+o];
    out_rec[(size_t)b*INDIM + tid] = r;
  }
}

// ======================= launch =======================
extern "C" void kernel_launch(void* const* d_in, const int* in_sizes, int n_in,
                              void* d_out, int out_size, void* d_ws, size_t ws_size,
                              hipStream_t stream){
  const float* x      = (const float*)d_in[0];
  const float* y      = (const float*)d_in[1];
  const float* init_w = (const float*)d_in[2];
  const float* init_b = (const float*)d_in[3];
  const float* eg     = (const float*)d_in[4];
  const float* ebv    = (const float*)d_in[5];
  const float* pf     = (const float*)d_in[6];
  const float* rw     = (const float*)d_in[7];
  const float* thr    = (const float*)d_in[8];
  const float* lv     = (const float*)d_in[9];
  const float* cg     = (const float*)d_in[10];
  const float* cbv    = (const float*)d_in[11];
  const float* m1w    = (const float*)d_in[12];
  const float* f1w    = (const float*)d_in[13];
  const float* f1b    = (const float*)d_in[14];
  const float* g1     = (const float*)d_in[15];
  const float* b1     = (const float*)d_in[16];
  const float* m2w    = (const float*)d_in[17];
  const float* f2w    = (const float*)d_in[18];
  const float* f2b    = (const float*)d_in[19];
  const float* g2     = (const float*)d_in[20];
  const float* b2v    = (const float*)d_in[21];
  const float* dw     = (const float*)d_in[22];
  const float* db     = (const float*)d_in[23];
  char* ws = (char*)d_ws;
  float* out = (float*)d_out;
  (void)in_sizes; (void)n_in; (void)out_size;

  // layout: [w2, caps, priors, m1, m2, lh, hsel, h1, s1, h2, s2]
  size_t offs[11];
  auto layout = [&](size_t nrows)->size_t{
    size_t o = 0; int i = 0;
    auto put = [&](size_t bytes){ offs[i++] = o; o = (o + bytes + 255) & ~(size_t)255; };
    put((size_t)MM*256*DDP*sizeof(__half));
    put((size_t)MM*nrows*DDP*sizeof(__half));
    put((size_t)nrows*MM*256*sizeof(__half));
    put(192*sizeof(float));
    put(240*sizeof(float));
    put(512*sizeof(float));
    put((size_t)BATCH*64*sizeof(float));
    put((size_t)BATCH*96*sizeof(float));
    put(16*96*2*sizeof(float));
    put((size_t)BATCH*192*sizeof(float));
    put(16*192*2*sizeof(float));
    return o;
  };
  int nrows = BATCH, nchunk = 1;
  if (layout(BATCH) > ws_size){ nrows = 1024; nchunk = 4; layout(1024); }
  __half* w2   = (__half*)(ws + offs[0]);
  __half* caps = (__half*)(ws + offs[1]);
  __half* pri  = (__half*)(ws + offs[2]);
  float*  m1   = (float*)(ws + offs[3]);
  float*  m2   = (float*)(ws + offs[4]);
  float*  lh   = (float*)(ws + offs[5]);
  float*  hsel = (float*)(ws + offs[6]);
  float*  h1   = (float*)(ws + offs[7]);
  float*  s1   = (float*)(ws + offs[8]);
  float*  h2   = (float*)(ws + offs[9]);
  float*  s2   = (float*)(ws + offs[10]);

  k_pre<<<dim3(530), dim3(256), 0, stream>>>(rw, m1w, m2w, lv, w2, m1, m2, lh);

  for (int c = 0; c < nchunk; ++c){
    int b0 = c*nrows;
    k_caps<<<dim3(nrows), dim3(256), 0, stream>>>(x, init_w, init_b, eg, ebv, pf,
        caps, b0, nrows);
    k_gemm_mfma<<<dim3(nrows/64, MM), dim3(256), 0, stream>>>(
        (const f16*)caps, (const f16*)w2, pri, nrows);
    k_route<<<dim3(nrows), dim3(256), 0, stream>>>(pri, lh, thr, cg, cbv, y,
        out, hsel, b0);
  }

  k_h1<<<dim3((BATCH*96)/256), dim3(256), 0, stream>>>(hsel, m1, f1w, f1b, h1);
  k_stats<<<dim3(16*96), dim3(256), 0, stream>>>(h1, s1, 96);
  k_out1h2<<<dim3(BATCH), dim3(192), 0, stream>>>(hsel, h1, s1, g1, b1,
      m2, f2w, f2b, h2);
  k_stats<<<dim3(16*192), dim3(256), 0, stream>>>(h2, s2, 192);
  k_final<<<dim3(BATCH), dim3(128), 0, stream>>>(h2, s2, g2, b2v, dw, db,
      out + (size_t)BATCH*NCLS);
}